// Round 2
// baseline (550.461 us; speedup 1.0000x reference)
//
#include <hip/hip_runtime.h>
#include <hip/hip_bf16.h>
#include <math.h>

typedef unsigned short u16;
typedef short short8 __attribute__((ext_vector_type(8)));
typedef float floatx4 __attribute__((ext_vector_type(4)));

#define B_   2
#define S_   2048
#define DM_  2048
#define H_   16
#define KVH_ 4
#define HD_  128

__device__ __forceinline__ float bf2f(u16 v) {
  union { unsigned int u; float f; } x; x.u = ((unsigned int)v) << 16; return x.f;
}
__device__ __forceinline__ u16 f2bf(float f) {
  union { float f; unsigned int u; } x; x.f = f;
  unsigned int u = x.u;
  u += 0x7FFFu + ((u >> 16) & 1u);   // RNE; inputs finite
  return (u16)(u >> 16);
}

// async 16B global->LDS (lds dest = wave-uniform base + lane*16)
#define GLDS16(gp, lp) __builtin_amdgcn_global_load_lds( \
    (const __attribute__((address_space(1))) unsigned int*)(const void*)(gp), \
    (__attribute__((address_space(3))) unsigned int*)(void*)(lp), 16, 0, 0)

// ---------------------------------------------------------------------------
// f32 -> bf16 elementwise pack (x): 4 elems/thread
// ---------------------------------------------------------------------------
__global__ __launch_bounds__(256) void k_pack_x(
    const float* __restrict__ src, u16* __restrict__ dst, int n4)
{
  int i = blockIdx.x * 256 + threadIdx.x;
  if (i >= n4) return;
  const float4 v = ((const float4*)src)[i];
  u16 o[4] = { f2bf(v.x), f2bf(v.y), f2bf(v.z), f2bf(v.w) };
  *(unsigned long long*)(dst + (size_t)i * 4) = *(unsigned long long*)o;
}

// ---------------------------------------------------------------------------
// f32 transpose + cast: src R x C row-major (f32) -> dst C x R row-major (bf16)
// ---------------------------------------------------------------------------
__global__ __launch_bounds__(256) void k_transpose_f2b(
    const float* __restrict__ src, u16* __restrict__ dst, int R, int C)
{
  __shared__ float tile[32][33];
  int c0 = blockIdx.x * 32, r0 = blockIdx.y * 32;
  int tx = threadIdx.x, ty = threadIdx.y;   // 32 x 8
#pragma unroll
  for (int j = 0; j < 4; j++)
    tile[ty * 4 + j][tx] = src[(size_t)(r0 + ty * 4 + j) * C + c0 + tx];
  __syncthreads();
#pragma unroll
  for (int j = 0; j < 4; j++)
    dst[(size_t)(c0 + ty * 4 + j) * R + r0 + tx] = f2bf(tile[tx][ty * 4 + j]);
}

// ---------------------------------------------------------------------------
// GEMM: C[M][N] = A[M][K] * Bt[N][K]^T   (bf16 in, f32 accum, f32/bf16 out)
// 128x128 tile, BK=32, 4 waves in 2x2, 4x4 16x16 MFMA tiles per wave (m97)
// ---------------------------------------------------------------------------
__global__ __launch_bounds__(256) void k_gemm_bt(
    const u16* __restrict__ A, const u16* __restrict__ Bt,
    void* __restrict__ Cout, int M, int N, int K, int c_bf16)
{
  __shared__ u16 As[128 * 32];
  __shared__ u16 Bs[128 * 32];
  int tid = threadIdx.x;
  int lane = tid & 63;
  int quad = lane >> 4, l16 = lane & 15;
  int wid = tid >> 6;
  int m0 = blockIdx.y * 128, n0 = blockIdx.x * 128;
  int wm = (wid >> 1) * 64, wn = (wid & 1) * 64;

  floatx4 acc[4][4] = {};

  int arow = tid >> 2, acol = (tid & 3) * 8;   // 4 lanes x 16B per 64B k-row
  const u16* Ap = A + (size_t)(m0 + arow) * K + acol;
  const u16* Bp = Bt + (size_t)(n0 + arow) * K + acol;
  u16* AsW = As + tid * 8;
  u16* BsW = Bs + tid * 8;

  for (int kt = 0; kt < K; kt += 32) {
    __syncthreads();                       // protect LDS from prev iter readers
    GLDS16(Ap, AsW);
    GLDS16(Ap + (size_t)64 * K, AsW + 2048);
    GLDS16(Bp, BsW);
    GLDS16(Bp + (size_t)64 * K, BsW + 2048);
    Ap += 32; Bp += 32;
    __syncthreads();                       // drains vmcnt(0) before barrier

    short8 af[4], bfv[4];
#pragma unroll
    for (int mi = 0; mi < 4; mi++)
      af[mi] = *(const short8*)&As[(wm + mi * 16 + l16) * 32 + quad * 8];
#pragma unroll
    for (int ni = 0; ni < 4; ni++)
      bfv[ni] = *(const short8*)&Bs[(wn + ni * 16 + l16) * 32 + quad * 8];
#pragma unroll
    for (int mi = 0; mi < 4; mi++)
#pragma unroll
      for (int ni = 0; ni < 4; ni++)
        acc[mi][ni] = __builtin_amdgcn_mfma_f32_16x16x32_bf16(
            af[mi], bfv[ni], acc[mi][ni], 0, 0, 0);
  }

#pragma unroll
  for (int mi = 0; mi < 4; mi++)
#pragma unroll
    for (int ni = 0; ni < 4; ni++)
#pragma unroll
      for (int r = 0; r < 4; r++) {
        int row = m0 + wm + mi * 16 + quad * 4 + r;
        int col = n0 + wn + ni * 16 + l16;
        float v = acc[mi][ni][r];
        if (c_bf16) ((u16*)Cout)[(size_t)row * N + col] = f2bf(v);
        else        ((float*)Cout)[(size_t)row * N + col] = v;
      }
}

// ---------------------------------------------------------------------------
// RMSNorm + RoPE on the qkv GEMM output (bf16), emit bf16 q_rope / k_rope.
// One block per token m = b*S+s; 20 rows (16 q heads + 4 k heads) of HD=128.
// HD^-0.5 folded into q here (rotation commutes with scaling).
// ---------------------------------------------------------------------------
__global__ __launch_bounds__(256) void k_rmsrope(
    const u16* __restrict__ C1, const float* __restrict__ qs,
    const float* __restrict__ ks, u16* __restrict__ qr, u16* __restrict__ kr)
{
  int m = blockIdx.x;
  int lane = threadIdx.x & 63, wid = threadIdx.x >> 6;
  int pos = m & (S_ - 1);
  float ts = powf(10000.0f, (float)lane * (1.0f / 64.0f));
  float ang = (float)pos / ts;
  float sn = sinf(ang), cs = cosf(ang);
  for (int r = wid; r < H_ + KVH_; r += 4) {
    bool isq = r < H_;
    const u16* src = C1 + (size_t)m * 3072 + (isq ? r * HD_ : DM_ + (r - H_) * HD_);
    float x1 = bf2f(src[lane]), x2 = bf2f(src[lane + 64]);
    float ss = x1 * x1 + x2 * x2;
#pragma unroll
    for (int d = 1; d < 64; d <<= 1) ss += __shfl_xor(ss, d);
    float rs = rsqrtf(ss * (1.0f / 128.0f) + 1e-6f);
    const float* sc = isq ? qs : ks;
    float y1 = x1 * rs * sc[lane];
    float y2 = x2 * rs * sc[lane + 64];
    float o1 = y1 * cs - y2 * sn;
    float o2 = y2 * cs + y1 * sn;
    if (isq) { o1 *= 0.088388347648318447f; o2 *= 0.088388347648318447f; }
    u16* dst = isq ? (qr + ((size_t)m * H_ + r) * HD_)
                   : (kr + ((size_t)m * KVH_ + (r - H_)) * HD_);
    dst[lane]      = f2bf(o1);
    dst[lane + 64] = f2bf(o2);
  }
}

// ---------------------------------------------------------------------------
// Pack V (bf16 cols 2560..3071 of C1) into bf16 vt[b][kv][HD][S] (transposed)
// ---------------------------------------------------------------------------
__global__ __launch_bounds__(256) void k_pack_vt(
    const u16* __restrict__ C1, u16* __restrict__ vt)
{
  __shared__ u16 tile[32][33];
  int s0 = blockIdx.x * 32, h0 = blockIdx.y * 32;
  int bk = blockIdx.z;                 // b*KV + kv
  int b = bk >> 2, kv = bk & 3;
  int tx = threadIdx.x, ty = threadIdx.y;
#pragma unroll
  for (int j = 0; j < 4; j++)
    tile[ty * 4 + j][tx] =
        C1[(size_t)(b * S_ + s0 + ty * 4 + j) * 3072 + 2560 + kv * HD_ + h0 + tx];
  __syncthreads();
#pragma unroll
  for (int j = 0; j < 4; j++)
    vt[((size_t)bk * HD_ + h0 + ty * 4 + j) * S_ + s0 + tx] = tile[tx][ty * 4 + j];
}

// ---------------------------------------------------------------------------
// Flash attention (causal, GQA). Block = (q-tile of 64, head, batch).
// Each of 4 waves owns 16 q rows. KT=64 K/V tiles staged via global_load_lds.
// P goes through per-wave LDS to convert MFMA C-layout -> A-layout (m120).
// ---------------------------------------------------------------------------
__global__ __launch_bounds__(256) void k_flash(
    const u16* __restrict__ qr, const u16* __restrict__ kr,
    const u16* __restrict__ vt, u16* __restrict__ att)
{
  __shared__ u16 Ks[64 * 128];    // [s_local][hd]
  __shared__ u16 Vt[128 * 64];    // [hd][s_local]
  __shared__ u16 Ps[4][16 * 64];  // per-wave P tile [row][s_local]
  int tid = threadIdx.x, lane = tid & 63, wid = tid >> 6;
  int quad = lane >> 4, l16 = lane & 15;
  int q0 = blockIdx.x * 64, h = blockIdx.y, b = blockIdx.z;
  int kvh = h >> 2;                // G = 4

  short8 qf[4];
  {
    const u16* qb = qr + ((size_t)(b * S_ + q0 + wid * 16 + l16) * H_ + h) * HD_;
#pragma unroll
    for (int kk = 0; kk < 4; kk++)
      qf[kk] = *(const short8*)(qb + kk * 32 + quad * 8);
  }

  floatx4 accO[8] = {};
  float m_i[4] = { -__builtin_inff(), -__builtin_inff(), -__builtin_inff(), -__builtin_inff() };
  float l_i[4] = { 0.f, 0.f, 0.f, 0.f };

  int nkt = (q0 >> 6) + 1;         // causal: tiles with k0 <= q0
  for (int kt = 0; kt < nkt; kt++) {
    int k0 = kt * 64;
#pragma unroll
    for (int j = 0; j < 4; j++) {  // Ks: 64 rows x 256B
      int c = j * 256 + tid;
      GLDS16(kr + ((size_t)(b * S_ + k0 + (c >> 4)) * KVH_ + kvh) * HD_ + (c & 15) * 8,
             Ks + c * 8);
    }
#pragma unroll
    for (int j = 0; j < 4; j++) {  // Vt: 128 rows x 128B
      int c = j * 256 + tid;
      GLDS16(vt + ((size_t)(b * KVH_ + kvh) * HD_ + (c >> 3)) * S_ + k0 + (c & 7) * 8,
             Vt + c * 8);
    }
    __syncthreads();

    // S = Q K^T  (16 x 64 per wave)
    floatx4 sacc[4] = {};
#pragma unroll
    for (int kk = 0; kk < 4; kk++)
#pragma unroll
      for (int nt = 0; nt < 4; nt++) {
        short8 kf = *(const short8*)&Ks[(nt * 16 + l16) * 128 + kk * 32 + quad * 8];
        sacc[nt] = __builtin_amdgcn_mfma_f32_16x16x32_bf16(qf[kk], kf, sacc[nt], 0, 0, 0);
      }

    // online softmax per row (row = q0 + wid*16 + quad*4 + r)
    float alpha[4];
#pragma unroll
    for (int r = 0; r < 4; r++) {
      int row = q0 + wid * 16 + quad * 4 + r;
      float mx = -__builtin_inff();
#pragma unroll
      for (int nt = 0; nt < 4; nt++) {
        int col = k0 + nt * 16 + l16;
        mx = fmaxf(mx, (col <= row) ? sacc[nt][r] : -__builtin_inff());
      }
#pragma unroll
      for (int d = 1; d < 16; d <<= 1) mx = fmaxf(mx, __shfl_xor(mx, d));
      float mn = fmaxf(m_i[r], mx);
      float al = __expf(m_i[r] - mn);   // exp(-inf)=0 on first tile
      float rsum = 0.f;
#pragma unroll
      for (int nt = 0; nt < 4; nt++) {
        int col = k0 + nt * 16 + l16;
        float p = (col <= row) ? __expf(sacc[nt][r] - mn) : 0.f;
        rsum += p;
        Ps[wid][(quad * 4 + r) * 64 + nt * 16 + l16] = f2bf(p);
      }
#pragma unroll
      for (int d = 1; d < 16; d <<= 1) rsum += __shfl_xor(rsum, d);
      l_i[r] = l_i[r] * al + rsum;
      m_i[r] = mn;
      alpha[r] = al;
    }

#pragma unroll
    for (int ht = 0; ht < 8; ht++)
#pragma unroll
      for (int r = 0; r < 4; r++) accO[ht][r] *= alpha[r];

    // O += P V   (P from LDS in A-layout, Vt rows give B^T layout)
#pragma unroll
    for (int kk = 0; kk < 2; kk++) {
      short8 pf = *(const short8*)&Ps[wid][l16 * 64 + kk * 32 + quad * 8];
#pragma unroll
      for (int ht = 0; ht < 8; ht++) {
        short8 vf = *(const short8*)&Vt[(ht * 16 + l16) * 64 + kk * 32 + quad * 8];
        accO[ht] = __builtin_amdgcn_mfma_f32_16x16x32_bf16(pf, vf, accO[ht], 0, 0, 0);
      }
    }
    __syncthreads();   // before next tile overwrites Ks/Vt
  }

#pragma unroll
  for (int ht = 0; ht < 8; ht++)
#pragma unroll
    for (int r = 0; r < 4; r++) {
      int row = q0 + wid * 16 + quad * 4 + r;
      float o = accO[ht][r] / l_i[r];
      att[((size_t)(b * S_ + row) * H_ + h) * HD_ + ht * 16 + l16] = f2bf(o);
    }
}

// ---------------------------------------------------------------------------
extern "C" void kernel_launch(void* const* d_in, const int* in_sizes, int n_in,
                              void* d_out, int out_size, void* d_ws, size_t ws_size,
                              hipStream_t stream)
{
  const float* x  = (const float*)d_in[0];   // [B,S,DM] f32
  const float* wq = (const float*)d_in[1];   // [DM, H*HD] f32
  const float* wk = (const float*)d_in[2];   // [DM, KV*HD] f32
  const float* wv = (const float*)d_in[3];   // [DM, KV*HD] f32
  const float* wo = (const float*)d_in[4];   // [H*HD, DM] f32
  const float* qs = (const float*)d_in[5];   // [HD] f32
  const float* ks = (const float*)d_in[6];   // [HD] f32

  char* ws = (char*)d_ws;
  size_t off = 0;
  u16* x_bf   = (u16*)(ws + off); off += (size_t)4096 * 2048 * 2;   // x bf16
  u16* wqkv_t = (u16*)(ws + off); off += (size_t)3072 * 2048 * 2;   // [3072][2048]
  u16* wo_t   = (u16*)(ws + off); off += (size_t)2048 * 2048 * 2;   // [2048][2048]
  u16* C1     = (u16*)(ws + off); off += (size_t)4096 * 3072 * 2;   // qkv bf16
  u16* q_rope = (u16*)(ws + off); off += (size_t)4096 * 16 * 128 * 2;
  u16* k_rope = (u16*)(ws + off); off += (size_t)4096 * 4 * 128 * 2;
  u16* vt     = (u16*)(ws + off); off += (size_t)8 * 128 * 2048 * 2;
  u16* att    = (u16*)(ws + off); off += (size_t)4096 * 2048 * 2;

  // x -> bf16
  k_pack_x<<<8192, 256, 0, stream>>>(x, x_bf, 4096 * 2048 / 4);

  // weight packing: B^T layouts (f32 -> bf16 fused)
  k_transpose_f2b<<<dim3(64, 64), dim3(32, 8), 0, stream>>>(wq, wqkv_t, 2048, 2048);
  k_transpose_f2b<<<dim3(16, 64), dim3(32, 8), 0, stream>>>(wk, wqkv_t + (size_t)2048 * 2048, 2048, 512);
  k_transpose_f2b<<<dim3(16, 64), dim3(32, 8), 0, stream>>>(wv, wqkv_t + (size_t)2560 * 2048, 2048, 512);
  k_transpose_f2b<<<dim3(64, 64), dim3(32, 8), 0, stream>>>(wo, wo_t, 2048, 2048);

  // qkv = x @ [wq|wk|wv]  (bf16 out)
  k_gemm_bt<<<dim3(24, 32), 256, 0, stream>>>(x_bf, wqkv_t, C1, 4096, 3072, 2048, 1);

  k_rmsrope<<<4096, 256, 0, stream>>>(C1, qs, ks, q_rope, k_rope);
  k_pack_vt<<<dim3(64, 4, 8), dim3(32, 8), 0, stream>>>(C1, vt);

  k_flash<<<dim3(32, 16, 2), 256, 0, stream>>>(q_rope, k_rope, vt, att);

  // out = att @ wo  (f32 out, matching reference output dtype)
  k_gemm_bt<<<dim3(16, 32), 256, 0, stream>>>(att, wo_t, d_out, 4096, 2048, 2048, 0);

  (void)in_sizes; (void)n_in; (void)out_size; (void)ws_size;
}

// Round 3
// 432.475 us; speedup vs baseline: 1.2728x; 1.2728x over previous
//
#include <hip/hip_runtime.h>
#include <hip/hip_bf16.h>
#include <math.h>

typedef unsigned short u16;
typedef short short8 __attribute__((ext_vector_type(8)));
typedef float floatx4 __attribute__((ext_vector_type(4)));

#define B_   2
#define S_   2048
#define DM_  2048
#define H_   16
#define KVH_ 4
#define HD_  128

__device__ __forceinline__ float bf2f(u16 v) {
  union { unsigned int u; float f; } x; x.u = ((unsigned int)v) << 16; return x.f;
}
__device__ __forceinline__ u16 f2bf(float f) {
  union { float f; unsigned int u; } x; x.f = f;
  unsigned int u = x.u;
  u += 0x7FFFu + ((u >> 16) & 1u);   // RNE; inputs finite
  return (u16)(u >> 16);
}

// async 16B global->LDS (lds dest = wave-uniform base + lane*16)
#define GLDS16(gp, lp) __builtin_amdgcn_global_load_lds( \
    (const __attribute__((address_space(1))) unsigned int*)(const void*)(gp), \
    (__attribute__((address_space(3))) unsigned int*)(void*)(lp), 16, 0, 0)

// ---------------------------------------------------------------------------
// f32 -> bf16 elementwise pack (x): 4 elems/thread
// ---------------------------------------------------------------------------
__global__ __launch_bounds__(256) void k_pack_x(
    const float* __restrict__ src, u16* __restrict__ dst, int n4)
{
  int i = blockIdx.x * 256 + threadIdx.x;
  if (i >= n4) return;
  const float4 v = ((const float4*)src)[i];
  u16 o[4] = { f2bf(v.x), f2bf(v.y), f2bf(v.z), f2bf(v.w) };
  *(unsigned long long*)(dst + (size_t)i * 4) = *(unsigned long long*)o;
}

// ---------------------------------------------------------------------------
// f32 transpose + cast: src R x C row-major (f32) -> dst C x R row-major (bf16)
// ---------------------------------------------------------------------------
__global__ __launch_bounds__(256) void k_transpose_f2b(
    const float* __restrict__ src, u16* __restrict__ dst, int R, int C)
{
  __shared__ float tile[32][33];
  int c0 = blockIdx.x * 32, r0 = blockIdx.y * 32;
  int tx = threadIdx.x, ty = threadIdx.y;   // 32 x 8
#pragma unroll
  for (int j = 0; j < 4; j++)
    tile[ty * 4 + j][tx] = src[(size_t)(r0 + ty * 4 + j) * C + c0 + tx];
  __syncthreads();
#pragma unroll
  for (int j = 0; j < 4; j++)
    dst[(size_t)(c0 + ty * 4 + j) * R + r0 + tx] = f2bf(tile[tx][ty * 4 + j]);
}

// ---------------------------------------------------------------------------
// GEMM: C[M][N] = A[M][K] * Bt[N][K]^T   (bf16 in, f32 accum, f32/bf16 out)
// 128x128 tile, BK=32, 4 waves in 2x2, 4x4 16x16 MFMA tiles per wave (m97)
// LDS chunk-swizzle j ^ ((row>>1)&3): fragment reads 8-way -> 2-way (free)
// ---------------------------------------------------------------------------
__global__ __launch_bounds__(256) void k_gemm_bt(
    const u16* __restrict__ A, const u16* __restrict__ Bt,
    void* __restrict__ Cout, int M, int N, int K, int c_bf16)
{
  __shared__ u16 As[128 * 32];
  __shared__ u16 Bs[128 * 32];
  int tid = threadIdx.x;
  int lane = tid & 63;
  int quad = lane >> 4, l16 = lane & 15;
  int wid = tid >> 6;
  int m0 = blockIdx.y * 128, n0 = blockIdx.x * 128;
  int wm = (wid >> 1) * 64, wn = (wid & 1) * 64;

  floatx4 acc[4][4] = {};

  int arow = tid >> 2;                               // LDS slot row
  int gj = (tid & 3) ^ ((tid >> 3) & 3);             // swizzled global chunk
  const u16* Ap = A + (size_t)(m0 + arow) * K + gj * 8;
  const u16* Bp = Bt + (size_t)(n0 + arow) * K + gj * 8;
  u16* AsW = As + tid * 8;
  u16* BsW = Bs + tid * 8;
  int sw = (quad ^ ((l16 >> 1) & 3)) * 8;            // swizzled read chunk

  for (int kt = 0; kt < K; kt += 32) {
    __syncthreads();                       // protect LDS from prev iter readers
    GLDS16(Ap, AsW);
    GLDS16(Ap + (size_t)64 * K, AsW + 2048);
    GLDS16(Bp, BsW);
    GLDS16(Bp + (size_t)64 * K, BsW + 2048);
    Ap += 32; Bp += 32;
    __syncthreads();                       // drains vmcnt(0) before barrier

    short8 af[4], bfv[4];
#pragma unroll
    for (int mi = 0; mi < 4; mi++)
      af[mi] = *(const short8*)&As[(wm + mi * 16 + l16) * 32 + sw];
#pragma unroll
    for (int ni = 0; ni < 4; ni++)
      bfv[ni] = *(const short8*)&Bs[(wn + ni * 16 + l16) * 32 + sw];
#pragma unroll
    for (int mi = 0; mi < 4; mi++)
#pragma unroll
      for (int ni = 0; ni < 4; ni++)
        acc[mi][ni] = __builtin_amdgcn_mfma_f32_16x16x32_bf16(
            af[mi], bfv[ni], acc[mi][ni], 0, 0, 0);
  }

#pragma unroll
  for (int mi = 0; mi < 4; mi++)
#pragma unroll
    for (int ni = 0; ni < 4; ni++)
#pragma unroll
      for (int r = 0; r < 4; r++) {
        int row = m0 + wm + mi * 16 + quad * 4 + r;
        int col = n0 + wn + ni * 16 + l16;
        float v = acc[mi][ni][r];
        if (c_bf16) ((u16*)Cout)[(size_t)row * N + col] = f2bf(v);
        else        ((float*)Cout)[(size_t)row * N + col] = v;
      }
}

// ---------------------------------------------------------------------------
// RMSNorm + RoPE on the qkv GEMM output (bf16), emit bf16 q_rope / k_rope.
// ---------------------------------------------------------------------------
__global__ __launch_bounds__(256) void k_rmsrope(
    const u16* __restrict__ C1, const float* __restrict__ qs,
    const float* __restrict__ ks, u16* __restrict__ qr, u16* __restrict__ kr)
{
  int m = blockIdx.x;
  int lane = threadIdx.x & 63, wid = threadIdx.x >> 6;
  int pos = m & (S_ - 1);
  float ts = powf(10000.0f, (float)lane * (1.0f / 64.0f));
  float ang = (float)pos / ts;
  float sn = sinf(ang), cs = cosf(ang);
  for (int r = wid; r < H_ + KVH_; r += 4) {
    bool isq = r < H_;
    const u16* src = C1 + (size_t)m * 3072 + (isq ? r * HD_ : DM_ + (r - H_) * HD_);
    float x1 = bf2f(src[lane]), x2 = bf2f(src[lane + 64]);
    float ss = x1 * x1 + x2 * x2;
#pragma unroll
    for (int d = 1; d < 64; d <<= 1) ss += __shfl_xor(ss, d);
    float rs = rsqrtf(ss * (1.0f / 128.0f) + 1e-6f);
    const float* sc = isq ? qs : ks;
    float y1 = x1 * rs * sc[lane];
    float y2 = x2 * rs * sc[lane + 64];
    float o1 = y1 * cs - y2 * sn;
    float o2 = y2 * cs + y1 * sn;
    if (isq) { o1 *= 0.088388347648318447f; o2 *= 0.088388347648318447f; }
    u16* dst = isq ? (qr + ((size_t)m * H_ + r) * HD_)
                   : (kr + ((size_t)m * KVH_ + (r - H_)) * HD_);
    dst[lane]      = f2bf(o1);
    dst[lane + 64] = f2bf(o2);
  }
}

// ---------------------------------------------------------------------------
// Pack V (bf16 cols 2560..3071 of C1) into bf16 vt[b][kv][HD][S] (transposed)
// ---------------------------------------------------------------------------
__global__ __launch_bounds__(256) void k_pack_vt(
    const u16* __restrict__ C1, u16* __restrict__ vt)
{
  __shared__ u16 tile[32][33];
  int s0 = blockIdx.x * 32, h0 = blockIdx.y * 32;
  int bk = blockIdx.z;                 // b*KV + kv
  int b = bk >> 2, kv = bk & 3;
  int tx = threadIdx.x, ty = threadIdx.y;
#pragma unroll
  for (int j = 0; j < 4; j++)
    tile[ty * 4 + j][tx] =
        C1[(size_t)(b * S_ + s0 + ty * 4 + j) * 3072 + 2560 + kv * HD_ + h0 + tx];
  __syncthreads();
#pragma unroll
  for (int j = 0; j < 4; j++)
    vt[((size_t)bk * HD_ + h0 + ty * 4 + j) * S_ + s0 + tx] = tile[tx][ty * 4 + j];
}

// ---------------------------------------------------------------------------
// Flash attention, work-balanced: block i handles q-tiles {i, 31-i} sharing
// one K/V staging -> every block does exactly 33 tile-updates.
// LDS: Ks swizzle j^(row&15), Vt swizzle j^(row&7), Ps padded stride 72.
// ---------------------------------------------------------------------------
__device__ __forceinline__ void flash_step(
    const short8 qf[4], floatx4 accO[8], float m_i[4], float l_i[4],
    int qrow_hi,          // q0 + wid*16 + quad*4  (row = qrow_hi + r)
    int k0, bool diag, int quad, int l16,
    u16* __restrict__ PsW, const u16* __restrict__ Ks, const u16* __restrict__ Vt)
{
  floatx4 sacc[4] = {};
#pragma unroll
  for (int kk = 0; kk < 4; kk++)
#pragma unroll
    for (int nt = 0; nt < 4; nt++) {
      int row = nt * 16 + l16;
      short8 kf = *(const short8*)&Ks[row * 128 + (((kk * 4 + quad) ^ (row & 15)) * 8)];
      sacc[nt] = __builtin_amdgcn_mfma_f32_16x16x32_bf16(qf[kk], kf, sacc[nt], 0, 0, 0);
    }

  float alpha[4];
#pragma unroll
  for (int r = 0; r < 4; r++) {
    int row = qrow_hi + r;
    float mx = -__builtin_inff();
#pragma unroll
    for (int nt = 0; nt < 4; nt++) {
      float s = sacc[nt][r];
      if (diag) s = ((k0 + nt * 16 + l16) <= row) ? s : -__builtin_inff();
      sacc[nt][r] = s;
      mx = fmaxf(mx, s);
    }
#pragma unroll
    for (int d = 1; d < 16; d <<= 1) mx = fmaxf(mx, __shfl_xor(mx, d));
    float mn = fmaxf(m_i[r], mx);
    float al = __expf(m_i[r] - mn);   // exp(-inf)=0 on first tile
    float rsum = 0.f;
#pragma unroll
    for (int nt = 0; nt < 4; nt++) {
      float p = __expf(sacc[nt][r] - mn);
      rsum += p;
      PsW[(quad * 4 + r) * 72 + nt * 16 + l16] = f2bf(p);
    }
#pragma unroll
    for (int d = 1; d < 16; d <<= 1) rsum += __shfl_xor(rsum, d);
    l_i[r] = l_i[r] * al + rsum;
    m_i[r] = mn;
    alpha[r] = al;
  }

#pragma unroll
  for (int ht = 0; ht < 8; ht++)
#pragma unroll
    for (int r = 0; r < 4; r++) accO[ht][r] *= alpha[r];

#pragma unroll
  for (int kk = 0; kk < 2; kk++) {
    short8 pf = *(const short8*)&PsW[l16 * 72 + kk * 32 + quad * 8];
#pragma unroll
    for (int ht = 0; ht < 8; ht++) {
      int row = ht * 16 + l16;
      short8 vf = *(const short8*)&Vt[row * 64 + (((kk * 4 + quad) ^ (row & 7)) * 8)];
      accO[ht] = __builtin_amdgcn_mfma_f32_16x16x32_bf16(pf, vf, accO[ht], 0, 0, 0);
    }
  }
}

__global__ __launch_bounds__(256, 2) void k_flash(
    const u16* __restrict__ qr, const u16* __restrict__ kr,
    const u16* __restrict__ vt, u16* __restrict__ att)
{
  __shared__ u16 Ks[64 * 128];       // swizzled [s_local][hd]
  __shared__ u16 Vt[128 * 64];       // swizzled [hd][s_local]
  __shared__ u16 Ps[4][2][16 * 72];  // per-wave, per-group, padded rows
  int tid = threadIdx.x, lane = tid & 63, wid = tid >> 6;
  int quad = lane >> 4, l16 = lane & 15;
  int i = blockIdx.x, h = blockIdx.y, b = blockIdx.z;
  int kvh = h >> 2;                  // G = 4
  int qA0 = i * 64, qB0 = (31 - i) * 64;
  int limA = i, limB = 31 - i;

  short8 qfA[4], qfB[4];
  {
    const u16* qa = qr + ((size_t)(b * S_ + qA0 + wid * 16 + l16) * H_ + h) * HD_;
    const u16* qb = qr + ((size_t)(b * S_ + qB0 + wid * 16 + l16) * H_ + h) * HD_;
#pragma unroll
    for (int kk = 0; kk < 4; kk++) {
      qfA[kk] = *(const short8*)(qa + kk * 32 + quad * 8);
      qfB[kk] = *(const short8*)(qb + kk * 32 + quad * 8);
    }
  }

  floatx4 oA[8] = {}, oB[8] = {};
  float mA[4], lA[4], mB[4], lB[4];
#pragma unroll
  for (int r = 0; r < 4; r++) {
    mA[r] = mB[r] = -__builtin_inff();
    lA[r] = lB[r] = 0.f;
  }

  for (int kt = 0; kt <= limB; kt++) {
    int k0 = kt * 64;
#pragma unroll
    for (int j = 0; j < 4; j++) {     // Ks: 64 rows x 16 chunks, swizzled
      int c = j * 256 + tid;
      int r = c >> 4, gjc = (c & 15) ^ (r & 15);
      GLDS16(kr + ((size_t)(b * S_ + k0 + r) * KVH_ + kvh) * HD_ + gjc * 8,
             Ks + (size_t)c * 8);
    }
#pragma unroll
    for (int j = 0; j < 4; j++) {     // Vt: 128 rows x 8 chunks, swizzled
      int c = j * 256 + tid;
      int r = c >> 3, gjc = (c & 7) ^ (r & 7);
      GLDS16(vt + ((size_t)(b * KVH_ + kvh) * HD_ + r) * S_ + k0 + gjc * 8,
             Vt + (size_t)c * 8);
    }
    __syncthreads();

    flash_step(qfB, oB, mB, lB, qB0 + wid * 16 + quad * 4, k0, kt == limB,
               quad, l16, &Ps[wid][1][0], Ks, Vt);
    if (kt <= limA)
      flash_step(qfA, oA, mA, lA, qA0 + wid * 16 + quad * 4, k0, kt == limA,
                 quad, l16, &Ps[wid][0][0], Ks, Vt);
    __syncthreads();
  }

#pragma unroll
  for (int ht = 0; ht < 8; ht++)
#pragma unroll
    for (int r = 0; r < 4; r++) {
      int rowA = qA0 + wid * 16 + quad * 4 + r;
      int rowB = qB0 + wid * 16 + quad * 4 + r;
      att[((size_t)(b * S_ + rowA) * H_ + h) * HD_ + ht * 16 + l16] = f2bf(oA[ht][r] / lA[r]);
      att[((size_t)(b * S_ + rowB) * H_ + h) * HD_ + ht * 16 + l16] = f2bf(oB[ht][r] / lB[r]);
    }
}

// ---------------------------------------------------------------------------
extern "C" void kernel_launch(void* const* d_in, const int* in_sizes, int n_in,
                              void* d_out, int out_size, void* d_ws, size_t ws_size,
                              hipStream_t stream)
{
  const float* x  = (const float*)d_in[0];   // [B,S,DM] f32
  const float* wq = (const float*)d_in[1];   // [DM, H*HD] f32
  const float* wk = (const float*)d_in[2];   // [DM, KV*HD] f32
  const float* wv = (const float*)d_in[3];   // [DM, KV*HD] f32
  const float* wo = (const float*)d_in[4];   // [H*HD, DM] f32
  const float* qs = (const float*)d_in[5];   // [HD] f32
  const float* ks = (const float*)d_in[6];   // [HD] f32

  char* ws = (char*)d_ws;
  size_t off = 0;
  u16* x_bf   = (u16*)(ws + off); off += (size_t)4096 * 2048 * 2;   // x bf16
  u16* wqkv_t = (u16*)(ws + off); off += (size_t)3072 * 2048 * 2;   // [3072][2048]
  u16* wo_t   = (u16*)(ws + off); off += (size_t)2048 * 2048 * 2;   // [2048][2048]
  u16* C1     = (u16*)(ws + off); off += (size_t)4096 * 3072 * 2;   // qkv bf16
  u16* q_rope = (u16*)(ws + off); off += (size_t)4096 * 16 * 128 * 2;
  u16* k_rope = (u16*)(ws + off); off += (size_t)4096 * 4 * 128 * 2;
  u16* vt     = (u16*)(ws + off); off += (size_t)8 * 128 * 2048 * 2;
  u16* att    = (u16*)(ws + off); off += (size_t)4096 * 2048 * 2;

  // x -> bf16
  k_pack_x<<<8192, 256, 0, stream>>>(x, x_bf, 4096 * 2048 / 4);

  // weight packing: B^T layouts (f32 -> bf16 fused)
  k_transpose_f2b<<<dim3(64, 64), dim3(32, 8), 0, stream>>>(wq, wqkv_t, 2048, 2048);
  k_transpose_f2b<<<dim3(16, 64), dim3(32, 8), 0, stream>>>(wk, wqkv_t + (size_t)2048 * 2048, 2048, 512);
  k_transpose_f2b<<<dim3(16, 64), dim3(32, 8), 0, stream>>>(wv, wqkv_t + (size_t)2560 * 2048, 2048, 512);
  k_transpose_f2b<<<dim3(64, 64), dim3(32, 8), 0, stream>>>(wo, wo_t, 2048, 2048);

  // qkv = x @ [wq|wk|wv]  (bf16 out)
  k_gemm_bt<<<dim3(24, 32), 256, 0, stream>>>(x_bf, wqkv_t, C1, 4096, 3072, 2048, 1);

  k_rmsrope<<<4096, 256, 0, stream>>>(C1, qs, ks, q_rope, k_rope);
  k_pack_vt<<<dim3(64, 4, 8), dim3(32, 8), 0, stream>>>(C1, vt);

  // paired causal flash: 16 q-pair blocks x 16 heads x 2 batch
  k_flash<<<dim3(16, 16, 2), 256, 0, stream>>>(q_rope, k_rope, vt, att);

  // out = att @ wo  (f32 out, matching reference output dtype)
  k_gemm_bt<<<dim3(16, 32), 256, 0, stream>>>(att, wo_t, d_out, 4096, 2048, 2048, 0);

  (void)in_sizes; (void)n_in; (void)out_size; (void)ws_size;
}

// Round 4
// 427.273 us; speedup vs baseline: 1.2883x; 1.0122x over previous
//
#include <hip/hip_runtime.h>
#include <hip/hip_bf16.h>
#include <math.h>

typedef unsigned short u16;
typedef short short8 __attribute__((ext_vector_type(8)));
typedef float floatx4 __attribute__((ext_vector_type(4)));

#define B_   2
#define S_   2048
#define DM_  2048
#define H_   16
#define KVH_ 4
#define HD_  128

__device__ __forceinline__ float bf2f(u16 v) {
  union { unsigned int u; float f; } x; x.u = ((unsigned int)v) << 16; return x.f;
}
__device__ __forceinline__ u16 f2bf(float f) {
  union { float f; unsigned int u; } x; x.f = f;
  unsigned int u = x.u;
  u += 0x7FFFu + ((u >> 16) & 1u);   // RNE; inputs finite
  return (u16)(u >> 16);
}

// async 16B global->LDS (lds dest = wave-uniform base + lane*16)
#define GLDS16(gp, lp) __builtin_amdgcn_global_load_lds( \
    (const __attribute__((address_space(1))) unsigned int*)(const void*)(gp), \
    (__attribute__((address_space(3))) unsigned int*)(void*)(lp), 16, 0, 0)

// ---------------------------------------------------------------------------
// f32 -> bf16 elementwise pack (x): 4 elems/thread
// ---------------------------------------------------------------------------
__global__ __launch_bounds__(256) void k_pack_x(
    const float* __restrict__ src, u16* __restrict__ dst, int n4)
{
  int i = blockIdx.x * 256 + threadIdx.x;
  if (i >= n4) return;
  const float4 v = ((const float4*)src)[i];
  u16 o[4] = { f2bf(v.x), f2bf(v.y), f2bf(v.z), f2bf(v.w) };
  *(unsigned long long*)(dst + (size_t)i * 4) = *(unsigned long long*)o;
}

// ---------------------------------------------------------------------------
// f32 transpose + cast: src R x C row-major (f32) -> dst C x R row-major (bf16)
// ---------------------------------------------------------------------------
__global__ __launch_bounds__(256) void k_transpose_f2b(
    const float* __restrict__ src, u16* __restrict__ dst, int R, int C)
{
  __shared__ float tile[32][33];
  int c0 = blockIdx.x * 32, r0 = blockIdx.y * 32;
  int tx = threadIdx.x, ty = threadIdx.y;   // 32 x 8
#pragma unroll
  for (int j = 0; j < 4; j++)
    tile[ty * 4 + j][tx] = src[(size_t)(r0 + ty * 4 + j) * C + c0 + tx];
  __syncthreads();
#pragma unroll
  for (int j = 0; j < 4; j++)
    dst[(size_t)(c0 + ty * 4 + j) * R + r0 + tx] = f2bf(tile[tx][ty * 4 + j]);
}

// ---------------------------------------------------------------------------
// GEMM: C[M][N] = A[M][K] * Bt[N][K]^T   (bf16 in, f32 accum, f32/bf16 out)
// 128x128 tile, BK=32, 4 waves in 2x2, 4x4 16x16 MFMA tiles per wave (m97)
// LDS chunk-swizzle j ^ ((row>>1)&3): fragment reads 8-way -> 2-way (free)
// ---------------------------------------------------------------------------
__global__ __launch_bounds__(256) void k_gemm_bt(
    const u16* __restrict__ A, const u16* __restrict__ Bt,
    void* __restrict__ Cout, int M, int N, int K, int c_bf16)
{
  __shared__ u16 As[128 * 32];
  __shared__ u16 Bs[128 * 32];
  int tid = threadIdx.x;
  int lane = tid & 63;
  int quad = lane >> 4, l16 = lane & 15;
  int wid = tid >> 6;
  int m0 = blockIdx.y * 128, n0 = blockIdx.x * 128;
  int wm = (wid >> 1) * 64, wn = (wid & 1) * 64;

  floatx4 acc[4][4] = {};

  int arow = tid >> 2;                               // LDS slot row
  int gj = (tid & 3) ^ ((tid >> 3) & 3);             // swizzled global chunk
  const u16* Ap = A + (size_t)(m0 + arow) * K + gj * 8;
  const u16* Bp = Bt + (size_t)(n0 + arow) * K + gj * 8;
  u16* AsW = As + tid * 8;
  u16* BsW = Bs + tid * 8;
  int sw = (quad ^ ((l16 >> 1) & 3)) * 8;            // swizzled read chunk

  for (int kt = 0; kt < K; kt += 32) {
    __syncthreads();                       // protect LDS from prev iter readers
    GLDS16(Ap, AsW);
    GLDS16(Ap + (size_t)64 * K, AsW + 2048);
    GLDS16(Bp, BsW);
    GLDS16(Bp + (size_t)64 * K, BsW + 2048);
    Ap += 32; Bp += 32;
    __syncthreads();                       // drains vmcnt(0) before barrier

    short8 af[4], bfv[4];
#pragma unroll
    for (int mi = 0; mi < 4; mi++)
      af[mi] = *(const short8*)&As[(wm + mi * 16 + l16) * 32 + sw];
#pragma unroll
    for (int ni = 0; ni < 4; ni++)
      bfv[ni] = *(const short8*)&Bs[(wn + ni * 16 + l16) * 32 + sw];
#pragma unroll
    for (int mi = 0; mi < 4; mi++)
#pragma unroll
      for (int ni = 0; ni < 4; ni++)
        acc[mi][ni] = __builtin_amdgcn_mfma_f32_16x16x32_bf16(
            af[mi], bfv[ni], acc[mi][ni], 0, 0, 0);
  }

#pragma unroll
  for (int mi = 0; mi < 4; mi++)
#pragma unroll
    for (int ni = 0; ni < 4; ni++)
#pragma unroll
      for (int r = 0; r < 4; r++) {
        int row = m0 + wm + mi * 16 + quad * 4 + r;
        int col = n0 + wn + ni * 16 + l16;
        float v = acc[mi][ni][r];
        if (c_bf16) ((u16*)Cout)[(size_t)row * N + col] = f2bf(v);
        else        ((float*)Cout)[(size_t)row * N + col] = v;
      }
}

// ---------------------------------------------------------------------------
// RMSNorm + RoPE on the qkv GEMM output (bf16), emit bf16 q_rope / k_rope.
// ---------------------------------------------------------------------------
__global__ __launch_bounds__(256) void k_rmsrope(
    const u16* __restrict__ C1, const float* __restrict__ qs,
    const float* __restrict__ ks, u16* __restrict__ qr, u16* __restrict__ kr)
{
  int m = blockIdx.x;
  int lane = threadIdx.x & 63, wid = threadIdx.x >> 6;
  int pos = m & (S_ - 1);
  float ts = powf(10000.0f, (float)lane * (1.0f / 64.0f));
  float ang = (float)pos / ts;
  float sn = sinf(ang), cs = cosf(ang);
  for (int r = wid; r < H_ + KVH_; r += 4) {
    bool isq = r < H_;
    const u16* src = C1 + (size_t)m * 3072 + (isq ? r * HD_ : DM_ + (r - H_) * HD_);
    float x1 = bf2f(src[lane]), x2 = bf2f(src[lane + 64]);
    float ss = x1 * x1 + x2 * x2;
#pragma unroll
    for (int d = 1; d < 64; d <<= 1) ss += __shfl_xor(ss, d);
    float rs = rsqrtf(ss * (1.0f / 128.0f) + 1e-6f);
    const float* sc = isq ? qs : ks;
    float y1 = x1 * rs * sc[lane];
    float y2 = x2 * rs * sc[lane + 64];
    float o1 = y1 * cs - y2 * sn;
    float o2 = y2 * cs + y1 * sn;
    if (isq) { o1 *= 0.088388347648318447f; o2 *= 0.088388347648318447f; }
    u16* dst = isq ? (qr + ((size_t)m * H_ + r) * HD_)
                   : (kr + ((size_t)m * KVH_ + (r - H_)) * HD_);
    dst[lane]      = f2bf(o1);
    dst[lane + 64] = f2bf(o2);
  }
}

// ---------------------------------------------------------------------------
// Pack V (bf16 cols 2560..3071 of C1) into bf16 vt[b][kv][HD][S] (transposed)
// ---------------------------------------------------------------------------
__global__ __launch_bounds__(256) void k_pack_vt(
    const u16* __restrict__ C1, u16* __restrict__ vt)
{
  __shared__ u16 tile[32][33];
  int s0 = blockIdx.x * 32, h0 = blockIdx.y * 32;
  int bk = blockIdx.z;                 // b*KV + kv
  int b = bk >> 2, kv = bk & 3;
  int tx = threadIdx.x, ty = threadIdx.y;
#pragma unroll
  for (int j = 0; j < 4; j++)
    tile[ty * 4 + j][tx] =
        C1[(size_t)(b * S_ + s0 + ty * 4 + j) * 3072 + 2560 + kv * HD_ + h0 + tx];
  __syncthreads();
#pragma unroll
  for (int j = 0; j < 4; j++)
    vt[((size_t)bk * HD_ + h0 + ty * 4 + j) * S_ + s0 + tx] = tile[tx][ty * 4 + j];
}

// ---------------------------------------------------------------------------
// Flash attention: ONE 64-row q-tile per block (low reg pressure, no spills).
// Grid balance: tile = 31 - blockIdx.x so longest tiles dispatch first.
// LDS: Ks swizzle j^(row&15), Vt swizzle j^(row&7), Ps padded stride 72.
// ---------------------------------------------------------------------------
__global__ __launch_bounds__(256, 3) void k_flash(
    const u16* __restrict__ qr, const u16* __restrict__ kr,
    const u16* __restrict__ vt, u16* __restrict__ att)
{
  __shared__ u16 Ks[64 * 128];       // swizzled [s_local][hd]
  __shared__ u16 Vt[128 * 64];       // swizzled [hd][s_local]
  __shared__ u16 Ps[4][16 * 72];     // per-wave P tile, padded rows
  int tid = threadIdx.x, lane = tid & 63, wid = tid >> 6;
  int quad = lane >> 4, l16 = lane & 15;
  int it = 31 - blockIdx.x;          // longest-first dispatch
  int h = blockIdx.y, b = blockIdx.z;
  int kvh = h >> 2;                  // G = 4
  int q0 = it * 64;

  short8 qf[4];
  {
    const u16* qb = qr + ((size_t)(b * S_ + q0 + wid * 16 + l16) * H_ + h) * HD_;
#pragma unroll
    for (int kk = 0; kk < 4; kk++)
      qf[kk] = *(const short8*)(qb + kk * 32 + quad * 8);
  }

  floatx4 accO[8] = {};
  float m_i[4] = { -__builtin_inff(), -__builtin_inff(), -__builtin_inff(), -__builtin_inff() };
  float l_i[4] = { 0.f, 0.f, 0.f, 0.f };
  u16* PsW = &Ps[wid][0];
  int qrow_hi = q0 + wid * 16 + quad * 4;

  for (int kt = 0; kt <= it; kt++) {
    int k0 = kt * 64;
#pragma unroll
    for (int j = 0; j < 4; j++) {     // Ks: 64 rows x 16 chunks, swizzled
      int c = j * 256 + tid;
      int r = c >> 4, gjc = (c & 15) ^ (r & 15);
      GLDS16(kr + ((size_t)(b * S_ + k0 + r) * KVH_ + kvh) * HD_ + gjc * 8,
             Ks + (size_t)c * 8);
    }
#pragma unroll
    for (int j = 0; j < 4; j++) {     // Vt: 128 rows x 8 chunks, swizzled
      int c = j * 256 + tid;
      int r = c >> 3, gjc = (c & 7) ^ (r & 7);
      GLDS16(vt + ((size_t)(b * KVH_ + kvh) * HD_ + r) * S_ + k0 + gjc * 8,
             Vt + (size_t)c * 8);
    }
    __syncthreads();

    // S = Q K^T  (16 x 64 per wave)
    floatx4 sacc[4] = {};
#pragma unroll
    for (int kk = 0; kk < 4; kk++)
#pragma unroll
      for (int nt = 0; nt < 4; nt++) {
        int row = nt * 16 + l16;
        short8 kf = *(const short8*)&Ks[row * 128 + (((kk * 4 + quad) ^ (row & 15)) * 8)];
        sacc[nt] = __builtin_amdgcn_mfma_f32_16x16x32_bf16(qf[kk], kf, sacc[nt], 0, 0, 0);
      }

    bool diag = (kt == it);
    float alpha[4];
#pragma unroll
    for (int r = 0; r < 4; r++) {
      int row = qrow_hi + r;
      float mx = -__builtin_inff();
#pragma unroll
      for (int nt = 0; nt < 4; nt++) {
        float s = sacc[nt][r];
        if (diag) s = ((k0 + nt * 16 + l16) <= row) ? s : -__builtin_inff();
        sacc[nt][r] = s;
        mx = fmaxf(mx, s);
      }
#pragma unroll
      for (int d = 1; d < 16; d <<= 1) mx = fmaxf(mx, __shfl_xor(mx, d));
      float mn = fmaxf(m_i[r], mx);
      float al = __expf(m_i[r] - mn);   // exp(-inf)=0 on first tile
      float rsum = 0.f;
#pragma unroll
      for (int nt = 0; nt < 4; nt++) {
        float p = __expf(sacc[nt][r] - mn);
        rsum += p;
        PsW[(quad * 4 + r) * 72 + nt * 16 + l16] = f2bf(p);
      }
#pragma unroll
      for (int d = 1; d < 16; d <<= 1) rsum += __shfl_xor(rsum, d);
      l_i[r] = l_i[r] * al + rsum;
      m_i[r] = mn;
      alpha[r] = al;
    }

#pragma unroll
    for (int ht = 0; ht < 8; ht++)
#pragma unroll
      for (int r = 0; r < 4; r++) accO[ht][r] *= alpha[r];

    // O += P V  (P from per-wave LDS in A-layout, Vt rows give B^T layout)
#pragma unroll
    for (int kk = 0; kk < 2; kk++) {
      short8 pf = *(const short8*)&PsW[l16 * 72 + kk * 32 + quad * 8];
#pragma unroll
      for (int ht = 0; ht < 8; ht++) {
        int row = ht * 16 + l16;
        short8 vf = *(const short8*)&Vt[row * 64 + (((kk * 4 + quad) ^ (row & 7)) * 8)];
        accO[ht] = __builtin_amdgcn_mfma_f32_16x16x32_bf16(pf, vf, accO[ht], 0, 0, 0);
      }
    }
    __syncthreads();   // before next tile overwrites Ks/Vt
  }

#pragma unroll
  for (int ht = 0; ht < 8; ht++)
#pragma unroll
    for (int r = 0; r < 4; r++) {
      int row = qrow_hi + r;
      att[((size_t)(b * S_ + row) * H_ + h) * HD_ + ht * 16 + l16] = f2bf(accO[ht][r] / l_i[r]);
    }
}

// ---------------------------------------------------------------------------
extern "C" void kernel_launch(void* const* d_in, const int* in_sizes, int n_in,
                              void* d_out, int out_size, void* d_ws, size_t ws_size,
                              hipStream_t stream)
{
  const float* x  = (const float*)d_in[0];   // [B,S,DM] f32
  const float* wq = (const float*)d_in[1];   // [DM, H*HD] f32
  const float* wk = (const float*)d_in[2];   // [DM, KV*HD] f32
  const float* wv = (const float*)d_in[3];   // [DM, KV*HD] f32
  const float* wo = (const float*)d_in[4];   // [H*HD, DM] f32
  const float* qs = (const float*)d_in[5];   // [HD] f32
  const float* ks = (const float*)d_in[6];   // [HD] f32

  char* ws = (char*)d_ws;
  size_t off = 0;
  u16* x_bf   = (u16*)(ws + off); off += (size_t)4096 * 2048 * 2;   // x bf16
  u16* wqkv_t = (u16*)(ws + off); off += (size_t)3072 * 2048 * 2;   // [3072][2048]
  u16* wo_t   = (u16*)(ws + off); off += (size_t)2048 * 2048 * 2;   // [2048][2048]
  u16* C1     = (u16*)(ws + off); off += (size_t)4096 * 3072 * 2;   // qkv bf16
  u16* q_rope = (u16*)(ws + off); off += (size_t)4096 * 16 * 128 * 2;
  u16* k_rope = (u16*)(ws + off); off += (size_t)4096 * 4 * 128 * 2;
  u16* vt     = (u16*)(ws + off); off += (size_t)8 * 128 * 2048 * 2;
  u16* att    = (u16*)(ws + off); off += (size_t)4096 * 2048 * 2;

  // x -> bf16
  k_pack_x<<<8192, 256, 0, stream>>>(x, x_bf, 4096 * 2048 / 4);

  // weight packing: B^T layouts (f32 -> bf16 fused)
  k_transpose_f2b<<<dim3(64, 64), dim3(32, 8), 0, stream>>>(wq, wqkv_t, 2048, 2048);
  k_transpose_f2b<<<dim3(16, 64), dim3(32, 8), 0, stream>>>(wk, wqkv_t + (size_t)2048 * 2048, 2048, 512);
  k_transpose_f2b<<<dim3(16, 64), dim3(32, 8), 0, stream>>>(wv, wqkv_t + (size_t)2560 * 2048, 2048, 512);
  k_transpose_f2b<<<dim3(64, 64), dim3(32, 8), 0, stream>>>(wo, wo_t, 2048, 2048);

  // qkv = x @ [wq|wk|wv]  (bf16 out)
  k_gemm_bt<<<dim3(24, 32), 256, 0, stream>>>(x_bf, wqkv_t, C1, 4096, 3072, 2048, 1);

  k_rmsrope<<<4096, 256, 0, stream>>>(C1, qs, ks, q_rope, k_rope);
  k_pack_vt<<<dim3(64, 4, 8), dim3(32, 8), 0, stream>>>(C1, vt);

  // causal flash: 32 q-tiles (longest-first) x 16 heads x 2 batch
  k_flash<<<dim3(32, 16, 2), 256, 0, stream>>>(q_rope, k_rope, vt, att);

  // out = att @ wo  (f32 out, matching reference output dtype)
  k_gemm_bt<<<dim3(16, 32), 256, 0, stream>>>(att, wo_t, d_out, 4096, 2048, 2048, 0);

  (void)in_sizes; (void)n_in; (void)out_size; (void)ws_size;
}

// Round 5
// 421.100 us; speedup vs baseline: 1.3072x; 1.0147x over previous
//
#include <hip/hip_runtime.h>
#include <hip/hip_bf16.h>
#include <math.h>

typedef unsigned short u16;
typedef short short8 __attribute__((ext_vector_type(8)));
typedef float floatx4 __attribute__((ext_vector_type(4)));

#define B_   2
#define S_   2048
#define DM_  2048
#define H_   16
#define KVH_ 4
#define HD_  128

__device__ __forceinline__ float bf2f(u16 v) {
  union { unsigned int u; float f; } x; x.u = ((unsigned int)v) << 16; return x.f;
}
__device__ __forceinline__ u16 f2bf(float f) {
  union { float f; unsigned int u; } x; x.f = f;
  unsigned int u = x.u;
  u += 0x7FFFu + ((u >> 16) & 1u);   // RNE; inputs finite
  return (u16)(u >> 16);
}

// async 16B global->LDS (lds dest = wave-uniform base + lane*16)
#define GLDS16(gp, lp) __builtin_amdgcn_global_load_lds( \
    (const __attribute__((address_space(1))) unsigned int*)(const void*)(gp), \
    (__attribute__((address_space(3))) unsigned int*)(void*)(lp), 16, 0, 0)

// ---------------------------------------------------------------------------
// f32 -> bf16 elementwise pack (x): 4 elems/thread
// ---------------------------------------------------------------------------
__global__ __launch_bounds__(256) void k_pack_x(
    const float* __restrict__ src, u16* __restrict__ dst, int n4)
{
  int i = blockIdx.x * 256 + threadIdx.x;
  if (i >= n4) return;
  const float4 v = ((const float4*)src)[i];
  u16 o[4] = { f2bf(v.x), f2bf(v.y), f2bf(v.z), f2bf(v.w) };
  *(unsigned long long*)(dst + (size_t)i * 4) = *(unsigned long long*)o;
}

// ---------------------------------------------------------------------------
// f32 transpose + cast: src R x C row-major (f32) -> dst C x R row-major (bf16)
// ---------------------------------------------------------------------------
__global__ __launch_bounds__(256) void k_transpose_f2b(
    const float* __restrict__ src, u16* __restrict__ dst, int R, int C)
{
  __shared__ float tile[32][33];
  int c0 = blockIdx.x * 32, r0 = blockIdx.y * 32;
  int tx = threadIdx.x, ty = threadIdx.y;   // 32 x 8
#pragma unroll
  for (int j = 0; j < 4; j++)
    tile[ty * 4 + j][tx] = src[(size_t)(r0 + ty * 4 + j) * C + c0 + tx];
  __syncthreads();
#pragma unroll
  for (int j = 0; j < 4; j++)
    dst[(size_t)(c0 + ty * 4 + j) * R + r0 + tx] = f2bf(tile[tx][ty * 4 + j]);
}

// ---------------------------------------------------------------------------
// GEMM: C[M][N] = A[M][K] * Bt[N][K]^T   (bf16 in, f32 accum, f32/bf16 out)
// 128x128 tile, BK=32, 4 waves in 2x2, 4x4 16x16 MFMA tiles per wave (m97)
// LDS chunk-swizzle j ^ ((row>>1)&3): fragment reads 8-way -> 2-way (free)
// ---------------------------------------------------------------------------
__global__ __launch_bounds__(256) void k_gemm_bt(
    const u16* __restrict__ A, const u16* __restrict__ Bt,
    void* __restrict__ Cout, int M, int N, int K, int c_bf16)
{
  __shared__ u16 As[128 * 32];
  __shared__ u16 Bs[128 * 32];
  int tid = threadIdx.x;
  int lane = tid & 63;
  int quad = lane >> 4, l16 = lane & 15;
  int wid = tid >> 6;
  int m0 = blockIdx.y * 128, n0 = blockIdx.x * 128;
  int wm = (wid >> 1) * 64, wn = (wid & 1) * 64;

  floatx4 acc[4][4] = {};

  int arow = tid >> 2;                               // LDS slot row
  int gj = (tid & 3) ^ ((tid >> 3) & 3);             // swizzled global chunk
  const u16* Ap = A + (size_t)(m0 + arow) * K + gj * 8;
  const u16* Bp = Bt + (size_t)(n0 + arow) * K + gj * 8;
  u16* AsW = As + tid * 8;
  u16* BsW = Bs + tid * 8;
  int sw = (quad ^ ((l16 >> 1) & 3)) * 8;            // swizzled read chunk

  for (int kt = 0; kt < K; kt += 32) {
    __syncthreads();                       // protect LDS from prev iter readers
    GLDS16(Ap, AsW);
    GLDS16(Ap + (size_t)64 * K, AsW + 2048);
    GLDS16(Bp, BsW);
    GLDS16(Bp + (size_t)64 * K, BsW + 2048);
    Ap += 32; Bp += 32;
    __syncthreads();                       // drains vmcnt(0) before barrier

    short8 af[4], bfv[4];
#pragma unroll
    for (int mi = 0; mi < 4; mi++)
      af[mi] = *(const short8*)&As[(wm + mi * 16 + l16) * 32 + sw];
#pragma unroll
    for (int ni = 0; ni < 4; ni++)
      bfv[ni] = *(const short8*)&Bs[(wn + ni * 16 + l16) * 32 + sw];
#pragma unroll
    for (int mi = 0; mi < 4; mi++)
#pragma unroll
      for (int ni = 0; ni < 4; ni++)
        acc[mi][ni] = __builtin_amdgcn_mfma_f32_16x16x32_bf16(
            af[mi], bfv[ni], acc[mi][ni], 0, 0, 0);
  }

#pragma unroll
  for (int mi = 0; mi < 4; mi++)
#pragma unroll
    for (int ni = 0; ni < 4; ni++)
#pragma unroll
      for (int r = 0; r < 4; r++) {
        int row = m0 + wm + mi * 16 + quad * 4 + r;
        int col = n0 + wn + ni * 16 + l16;
        float v = acc[mi][ni][r];
        if (c_bf16) ((u16*)Cout)[(size_t)row * N + col] = f2bf(v);
        else        ((float*)Cout)[(size_t)row * N + col] = v;
      }
}

// ---------------------------------------------------------------------------
// RMSNorm + RoPE on the qkv GEMM output (bf16), emit bf16 q_rope / k_rope.
// ---------------------------------------------------------------------------
__global__ __launch_bounds__(256) void k_rmsrope(
    const u16* __restrict__ C1, const float* __restrict__ qs,
    const float* __restrict__ ks, u16* __restrict__ qr, u16* __restrict__ kr)
{
  int m = blockIdx.x;
  int lane = threadIdx.x & 63, wid = threadIdx.x >> 6;
  int pos = m & (S_ - 1);
  float ts = powf(10000.0f, (float)lane * (1.0f / 64.0f));
  float ang = (float)pos / ts;
  float sn = sinf(ang), cs = cosf(ang);
  for (int r = wid; r < H_ + KVH_; r += 4) {
    bool isq = r < H_;
    const u16* src = C1 + (size_t)m * 3072 + (isq ? r * HD_ : DM_ + (r - H_) * HD_);
    float x1 = bf2f(src[lane]), x2 = bf2f(src[lane + 64]);
    float ss = x1 * x1 + x2 * x2;
#pragma unroll
    for (int d = 1; d < 64; d <<= 1) ss += __shfl_xor(ss, d);
    float rs = rsqrtf(ss * (1.0f / 128.0f) + 1e-6f);
    const float* sc = isq ? qs : ks;
    float y1 = x1 * rs * sc[lane];
    float y2 = x2 * rs * sc[lane + 64];
    float o1 = y1 * cs - y2 * sn;
    float o2 = y2 * cs + y1 * sn;
    if (isq) { o1 *= 0.088388347648318447f; o2 *= 0.088388347648318447f; }
    u16* dst = isq ? (qr + ((size_t)m * H_ + r) * HD_)
                   : (kr + ((size_t)m * KVH_ + (r - H_)) * HD_);
    dst[lane]      = f2bf(o1);
    dst[lane + 64] = f2bf(o2);
  }
}

// ---------------------------------------------------------------------------
// Pack V (bf16 cols 2560..3071 of C1) into bf16 vt[b][kv][HD][S] (transposed)
// ---------------------------------------------------------------------------
__global__ __launch_bounds__(256) void k_pack_vt(
    const u16* __restrict__ C1, u16* __restrict__ vt)
{
  __shared__ u16 tile[32][33];
  int s0 = blockIdx.x * 32, h0 = blockIdx.y * 32;
  int bk = blockIdx.z;                 // b*KV + kv
  int b = bk >> 2, kv = bk & 3;
  int tx = threadIdx.x, ty = threadIdx.y;
#pragma unroll
  for (int j = 0; j < 4; j++)
    tile[ty * 4 + j][tx] =
        C1[(size_t)(b * S_ + s0 + ty * 4 + j) * 3072 + 2560 + kv * HD_ + h0 + tx];
  __syncthreads();
#pragma unroll
  for (int j = 0; j < 4; j++)
    vt[((size_t)bk * HD_ + h0 + ty * 4 + j) * S_ + s0 + tx] = tile[tx][ty * 4 + j];
}

// ---------------------------------------------------------------------------
// Flash attention, register-prefetch pipeline:
//   ds_write(tile kt) -> barrier -> issue global loads(kt+1) -> compute(kt)
// The vmcnt wait for kt+1 lands at next iteration's ds_write, i.e. AFTER the
// compute phase -> global latency hidden; barriers drain only lgkmcnt.
// One 64-row q-tile per block; grid tile = 31 - blockIdx.x (longest first).
// LDS: Ks swizzle j^(row&15), Vt swizzle j^(row&7), Ps padded stride 72.
// ---------------------------------------------------------------------------
__global__ __launch_bounds__(256, 3) void k_flash(
    const u16* __restrict__ qr, const u16* __restrict__ kr,
    const u16* __restrict__ vt, u16* __restrict__ att)
{
  __shared__ u16 Ks[64 * 128];       // swizzled [s_local][hd]
  __shared__ u16 Vt[128 * 64];       // swizzled [hd][s_local]
  __shared__ u16 Ps[4][16 * 72];     // per-wave P tile, padded rows
  int tid = threadIdx.x, lane = tid & 63, wid = tid >> 6;
  int quad = lane >> 4, l16 = lane & 15;
  int it = 31 - blockIdx.x;          // longest-first dispatch
  int h = blockIdx.y, b = blockIdx.z;
  int kvh = h >> 2;                  // G = 4
  int q0 = it * 64;

  short8 qf[4];
  {
    const u16* qb = qr + ((size_t)(b * S_ + q0 + wid * 16 + l16) * H_ + h) * HD_;
#pragma unroll
    for (int kk = 0; kk < 4; kk++)
      qf[kk] = *(const short8*)(qb + kk * 32 + quad * 8);
  }

  // prefetch pointers: chunk swizzle is j-independent, so 2 bases + strides.
  // Ks chunk (j,tid): row r = j*16 + (tid>>4), col chunk gjk = (tid&15)^((tid>>4)&15)
  // Vt chunk (j,tid): row r = j*32 + (tid>>3), col chunk gjv = (tid&7)^((tid>>3)&7)
  int gjk = (tid & 15) ^ ((tid >> 4) & 15);
  int gjv = (tid & 7) ^ ((tid >> 3) & 7);
  const u16* kp = kr + ((size_t)(b * S_ + (tid >> 4)) * KVH_ + kvh) * HD_ + gjk * 8;
  const u16* vp = vt + ((size_t)(b * KVH_ + kvh) * HD_ + (tid >> 3)) * S_ + gjv * 8;

  short8 pk[4], pv[4];
#pragma unroll
  for (int j = 0; j < 4; j++) {
    pk[j] = *(const short8*)(kp + (size_t)j * 16 * KVH_ * HD_);
    pv[j] = *(const short8*)(vp + (size_t)j * 32 * S_);
  }

  floatx4 accO[8] = {};
  float m_i[4] = { -__builtin_inff(), -__builtin_inff(), -__builtin_inff(), -__builtin_inff() };
  float l_i[4] = { 0.f, 0.f, 0.f, 0.f };
  u16* PsW = &Ps[wid][0];
  int qrow_hi = q0 + wid * 16 + quad * 4;

  for (int kt = 0; kt <= it; kt++) {
    int k0 = kt * 64;
    // commit prefetched tile to LDS (waits vmcnt here, after prev compute)
#pragma unroll
    for (int j = 0; j < 4; j++) {
      *(short8*)&Ks[(j * 256 + tid) * 8] = pk[j];
      *(short8*)&Vt[(j * 256 + tid) * 8] = pv[j];
    }
    __syncthreads();

    // issue next tile's loads; latency hidden behind compute below
    if (kt < it) {
      kp += (size_t)64 * KVH_ * HD_;
      vp += 64;
#pragma unroll
      for (int j = 0; j < 4; j++) {
        pk[j] = *(const short8*)(kp + (size_t)j * 16 * KVH_ * HD_);
        pv[j] = *(const short8*)(vp + (size_t)j * 32 * S_);
      }
    }

    // S = Q K^T  (16 x 64 per wave)
    floatx4 sacc[4] = {};
#pragma unroll
    for (int kk = 0; kk < 4; kk++)
#pragma unroll
      for (int nt = 0; nt < 4; nt++) {
        int row = nt * 16 + l16;
        short8 kf = *(const short8*)&Ks[row * 128 + (((kk * 4 + quad) ^ (row & 15)) * 8)];
        sacc[nt] = __builtin_amdgcn_mfma_f32_16x16x32_bf16(qf[kk], kf, sacc[nt], 0, 0, 0);
      }

    bool diag = (kt == it);
    float alpha[4];
#pragma unroll
    for (int r = 0; r < 4; r++) {
      int row = qrow_hi + r;
      float mx = -__builtin_inff();
#pragma unroll
      for (int nt = 0; nt < 4; nt++) {
        float s = sacc[nt][r];
        if (diag) s = ((k0 + nt * 16 + l16) <= row) ? s : -__builtin_inff();
        sacc[nt][r] = s;
        mx = fmaxf(mx, s);
      }
#pragma unroll
      for (int d = 1; d < 16; d <<= 1) mx = fmaxf(mx, __shfl_xor(mx, d));
      float mn = fmaxf(m_i[r], mx);
      float al = __expf(m_i[r] - mn);   // exp(-inf)=0 on first tile
      float rsum = 0.f;
#pragma unroll
      for (int nt = 0; nt < 4; nt++) {
        float p = __expf(sacc[nt][r] - mn);
        rsum += p;
        PsW[(quad * 4 + r) * 72 + nt * 16 + l16] = f2bf(p);
      }
#pragma unroll
      for (int d = 1; d < 16; d <<= 1) rsum += __shfl_xor(rsum, d);
      l_i[r] = l_i[r] * al + rsum;
      m_i[r] = mn;
      alpha[r] = al;
    }

#pragma unroll
    for (int ht = 0; ht < 8; ht++)
#pragma unroll
      for (int r = 0; r < 4; r++) accO[ht][r] *= alpha[r];

    // O += P V  (P from per-wave LDS in A-layout, Vt rows give B^T layout)
#pragma unroll
    for (int kk = 0; kk < 2; kk++) {
      short8 pf = *(const short8*)&PsW[l16 * 72 + kk * 32 + quad * 8];
#pragma unroll
      for (int ht = 0; ht < 8; ht++) {
        int row = ht * 16 + l16;
        short8 vf = *(const short8*)&Vt[row * 64 + (((kk * 4 + quad) ^ (row & 7)) * 8)];
        accO[ht] = __builtin_amdgcn_mfma_f32_16x16x32_bf16(pf, vf, accO[ht], 0, 0, 0);
      }
    }
    __syncthreads();   // before next tile overwrites Ks/Vt (lgkm only)
  }

#pragma unroll
  for (int ht = 0; ht < 8; ht++)
#pragma unroll
    for (int r = 0; r < 4; r++) {
      int row = qrow_hi + r;
      att[((size_t)(b * S_ + row) * H_ + h) * HD_ + ht * 16 + l16] = f2bf(accO[ht][r] / l_i[r]);
    }
}

// ---------------------------------------------------------------------------
extern "C" void kernel_launch(void* const* d_in, const int* in_sizes, int n_in,
                              void* d_out, int out_size, void* d_ws, size_t ws_size,
                              hipStream_t stream)
{
  const float* x  = (const float*)d_in[0];   // [B,S,DM] f32
  const float* wq = (const float*)d_in[1];   // [DM, H*HD] f32
  const float* wk = (const float*)d_in[2];   // [DM, KV*HD] f32
  const float* wv = (const float*)d_in[3];   // [DM, KV*HD] f32
  const float* wo = (const float*)d_in[4];   // [H*HD, DM] f32
  const float* qs = (const float*)d_in[5];   // [HD] f32
  const float* ks = (const float*)d_in[6];   // [HD] f32

  char* ws = (char*)d_ws;
  size_t off = 0;
  u16* x_bf   = (u16*)(ws + off); off += (size_t)4096 * 2048 * 2;   // x bf16
  u16* wqkv_t = (u16*)(ws + off); off += (size_t)3072 * 2048 * 2;   // [3072][2048]
  u16* wo_t   = (u16*)(ws + off); off += (size_t)2048 * 2048 * 2;   // [2048][2048]
  u16* C1     = (u16*)(ws + off); off += (size_t)4096 * 3072 * 2;   // qkv bf16
  u16* q_rope = (u16*)(ws + off); off += (size_t)4096 * 16 * 128 * 2;
  u16* k_rope = (u16*)(ws + off); off += (size_t)4096 * 4 * 128 * 2;
  u16* vt     = (u16*)(ws + off); off += (size_t)8 * 128 * 2048 * 2;
  u16* att    = (u16*)(ws + off); off += (size_t)4096 * 2048 * 2;

  // x -> bf16
  k_pack_x<<<8192, 256, 0, stream>>>(x, x_bf, 4096 * 2048 / 4);

  // weight packing: B^T layouts (f32 -> bf16 fused)
  k_transpose_f2b<<<dim3(64, 64), dim3(32, 8), 0, stream>>>(wq, wqkv_t, 2048, 2048);
  k_transpose_f2b<<<dim3(16, 64), dim3(32, 8), 0, stream>>>(wk, wqkv_t + (size_t)2048 * 2048, 2048, 512);
  k_transpose_f2b<<<dim3(16, 64), dim3(32, 8), 0, stream>>>(wv, wqkv_t + (size_t)2560 * 2048, 2048, 512);
  k_transpose_f2b<<<dim3(64, 64), dim3(32, 8), 0, stream>>>(wo, wo_t, 2048, 2048);

  // qkv = x @ [wq|wk|wv]  (bf16 out)
  k_gemm_bt<<<dim3(24, 32), 256, 0, stream>>>(x_bf, wqkv_t, C1, 4096, 3072, 2048, 1);

  k_rmsrope<<<4096, 256, 0, stream>>>(C1, qs, ks, q_rope, k_rope);
  k_pack_vt<<<dim3(64, 4, 8), dim3(32, 8), 0, stream>>>(C1, vt);

  // causal flash: 32 q-tiles (longest-first) x 16 heads x 2 batch
  k_flash<<<dim3(32, 16, 2), 256, 0, stream>>>(q_rope, k_rope, vt, att);

  // out = att @ wo  (f32 out, matching reference output dtype)
  k_gemm_bt<<<dim3(16, 32), 256, 0, stream>>>(att, wo_t, d_out, 4096, 2048, 2048, 0);

  (void)in_sizes; (void)n_in; (void)out_size; (void)ws_size;
}

// Round 6
// 350.766 us; speedup vs baseline: 1.5693x; 1.2005x over previous
//
#include <hip/hip_runtime.h>
#include <hip/hip_bf16.h>
#include <math.h>

typedef unsigned short u16;
typedef short short8 __attribute__((ext_vector_type(8)));
typedef float floatx4 __attribute__((ext_vector_type(4)));

#define B_   2
#define S_   2048
#define DM_  2048
#define H_   16
#define KVH_ 4
#define HD_  128

__device__ __forceinline__ float bf2f(u16 v) {
  union { unsigned int u; float f; } x; x.u = ((unsigned int)v) << 16; return x.f;
}
__device__ __forceinline__ u16 f2bf(float f) {
  union { float f; unsigned int u; } x; x.f = f;
  unsigned int u = x.u;
  u += 0x7FFFu + ((u >> 16) & 1u);   // RNE; inputs finite
  return (u16)(u >> 16);
}

// async 16B global->LDS (lds dest = wave-uniform base + lane*16)
#define GLDS16(gp, lp) __builtin_amdgcn_global_load_lds( \
    (const __attribute__((address_space(1))) unsigned int*)(const void*)(gp), \
    (__attribute__((address_space(3))) unsigned int*)(void*)(lp), 16, 0, 0)

// ---------------------------------------------------------------------------
// f32 -> bf16 elementwise pack (x): 4 elems/thread
// ---------------------------------------------------------------------------
__global__ __launch_bounds__(256) void k_pack_x(
    const float* __restrict__ src, u16* __restrict__ dst, int n4)
{
  int i = blockIdx.x * 256 + threadIdx.x;
  if (i >= n4) return;
  const float4 v = ((const float4*)src)[i];
  u16 o[4] = { f2bf(v.x), f2bf(v.y), f2bf(v.z), f2bf(v.w) };
  *(unsigned long long*)(dst + (size_t)i * 4) = *(unsigned long long*)o;
}

// ---------------------------------------------------------------------------
// f32 transpose + cast: src R x C row-major (f32) -> dst C x R row-major (bf16)
// ---------------------------------------------------------------------------
__global__ __launch_bounds__(256) void k_transpose_f2b(
    const float* __restrict__ src, u16* __restrict__ dst, int R, int C)
{
  __shared__ float tile[32][33];
  int c0 = blockIdx.x * 32, r0 = blockIdx.y * 32;
  int tx = threadIdx.x, ty = threadIdx.y;   // 32 x 8
#pragma unroll
  for (int j = 0; j < 4; j++)
    tile[ty * 4 + j][tx] = src[(size_t)(r0 + ty * 4 + j) * C + c0 + tx];
  __syncthreads();
#pragma unroll
  for (int j = 0; j < 4; j++)
    dst[(size_t)(c0 + ty * 4 + j) * R + r0 + tx] = f2bf(tile[tx][ty * 4 + j]);
}

// ---------------------------------------------------------------------------
// GEMM: C[M][N] = A[M][K] * Bt[N][K]^T   (bf16 in, f32 accum, f32/bf16 out)
// 128x128 tile, BK=32, 4 waves in 2x2, 4x4 16x16 MFMA tiles per wave (m97)
// LDS chunk-swizzle j ^ ((row>>1)&3): fragment reads 8-way -> 2-way (free)
// ---------------------------------------------------------------------------
__global__ __launch_bounds__(256) void k_gemm_bt(
    const u16* __restrict__ A, const u16* __restrict__ Bt,
    void* __restrict__ Cout, int M, int N, int K, int c_bf16)
{
  __shared__ u16 As[128 * 32];
  __shared__ u16 Bs[128 * 32];
  int tid = threadIdx.x;
  int lane = tid & 63;
  int quad = lane >> 4, l16 = lane & 15;
  int wid = tid >> 6;
  int m0 = blockIdx.y * 128, n0 = blockIdx.x * 128;
  int wm = (wid >> 1) * 64, wn = (wid & 1) * 64;

  floatx4 acc[4][4] = {};

  int arow = tid >> 2;                               // LDS slot row
  int gj = (tid & 3) ^ ((tid >> 3) & 3);             // swizzled global chunk
  const u16* Ap = A + (size_t)(m0 + arow) * K + gj * 8;
  const u16* Bp = Bt + (size_t)(n0 + arow) * K + gj * 8;
  u16* AsW = As + tid * 8;
  u16* BsW = Bs + tid * 8;
  int sw = (quad ^ ((l16 >> 1) & 3)) * 8;            // swizzled read chunk

  for (int kt = 0; kt < K; kt += 32) {
    __syncthreads();                       // protect LDS from prev iter readers
    GLDS16(Ap, AsW);
    GLDS16(Ap + (size_t)64 * K, AsW + 2048);
    GLDS16(Bp, BsW);
    GLDS16(Bp + (size_t)64 * K, BsW + 2048);
    Ap += 32; Bp += 32;
    __syncthreads();                       // drains vmcnt(0) before barrier

    short8 af[4], bfv[4];
#pragma unroll
    for (int mi = 0; mi < 4; mi++)
      af[mi] = *(const short8*)&As[(wm + mi * 16 + l16) * 32 + sw];
#pragma unroll
    for (int ni = 0; ni < 4; ni++)
      bfv[ni] = *(const short8*)&Bs[(wn + ni * 16 + l16) * 32 + sw];
#pragma unroll
    for (int mi = 0; mi < 4; mi++)
#pragma unroll
      for (int ni = 0; ni < 4; ni++)
        acc[mi][ni] = __builtin_amdgcn_mfma_f32_16x16x32_bf16(
            af[mi], bfv[ni], acc[mi][ni], 0, 0, 0);
  }

#pragma unroll
  for (int mi = 0; mi < 4; mi++)
#pragma unroll
    for (int ni = 0; ni < 4; ni++)
#pragma unroll
      for (int r = 0; r < 4; r++) {
        int row = m0 + wm + mi * 16 + quad * 4 + r;
        int col = n0 + wn + ni * 16 + l16;
        float v = acc[mi][ni][r];
        if (c_bf16) ((u16*)Cout)[(size_t)row * N + col] = f2bf(v);
        else        ((float*)Cout)[(size_t)row * N + col] = v;
      }
}

// ---------------------------------------------------------------------------
// RMSNorm + RoPE on the qkv GEMM output (bf16), emit bf16 q_rope / k_rope.
// ---------------------------------------------------------------------------
__global__ __launch_bounds__(256) void k_rmsrope(
    const u16* __restrict__ C1, const float* __restrict__ qs,
    const float* __restrict__ ks, u16* __restrict__ qr, u16* __restrict__ kr)
{
  int m = blockIdx.x;
  int lane = threadIdx.x & 63, wid = threadIdx.x >> 6;
  int pos = m & (S_ - 1);
  float ts = powf(10000.0f, (float)lane * (1.0f / 64.0f));
  float ang = (float)pos / ts;
  float sn = sinf(ang), cs = cosf(ang);
  for (int r = wid; r < H_ + KVH_; r += 4) {
    bool isq = r < H_;
    const u16* src = C1 + (size_t)m * 3072 + (isq ? r * HD_ : DM_ + (r - H_) * HD_);
    float x1 = bf2f(src[lane]), x2 = bf2f(src[lane + 64]);
    float ss = x1 * x1 + x2 * x2;
#pragma unroll
    for (int d = 1; d < 64; d <<= 1) ss += __shfl_xor(ss, d);
    float rs = rsqrtf(ss * (1.0f / 128.0f) + 1e-6f);
    const float* sc = isq ? qs : ks;
    float y1 = x1 * rs * sc[lane];
    float y2 = x2 * rs * sc[lane + 64];
    float o1 = y1 * cs - y2 * sn;
    float o2 = y2 * cs + y1 * sn;
    if (isq) { o1 *= 0.088388347648318447f; o2 *= 0.088388347648318447f; }
    u16* dst = isq ? (qr + ((size_t)m * H_ + r) * HD_)
                   : (kr + ((size_t)m * KVH_ + (r - H_)) * HD_);
    dst[lane]      = f2bf(o1);
    dst[lane + 64] = f2bf(o2);
  }
}

// ---------------------------------------------------------------------------
// Pack V (bf16 cols 2560..3071 of C1) into bf16 vt[b][kv][HD][S] (transposed)
// ---------------------------------------------------------------------------
__global__ __launch_bounds__(256) void k_pack_vt(
    const u16* __restrict__ C1, u16* __restrict__ vt)
{
  __shared__ u16 tile[32][33];
  int s0 = blockIdx.x * 32, h0 = blockIdx.y * 32;
  int bk = blockIdx.z;                 // b*KV + kv
  int b = bk >> 2, kv = bk & 3;
  int tx = threadIdx.x, ty = threadIdx.y;
#pragma unroll
  for (int j = 0; j < 4; j++)
    tile[ty * 4 + j][tx] =
        C1[(size_t)(b * S_ + s0 + ty * 4 + j) * 3072 + 2560 + kv * HD_ + h0 + tx];
  __syncthreads();
#pragma unroll
  for (int j = 0; j < 4; j++)
    vt[((size_t)bk * HD_ + h0 + ty * 4 + j) * S_ + s0 + tx] = tile[tx][ty * 4 + j];
}

// ---------------------------------------------------------------------------
// Flash attention, register-prefetch pipeline + GLOBAL longest-first order:
// flat grid.x = 1024; tier = bx>>5 (0..31) -> it = 31-tier; hb = bx&31.
// All 32 longest blocks (it=31, every (h,b)) dispatch first, shortest last.
// ---------------------------------------------------------------------------
__global__ __launch_bounds__(256, 3) void k_flash(
    const u16* __restrict__ qr, const u16* __restrict__ kr,
    const u16* __restrict__ vt, u16* __restrict__ att)
{
  __shared__ u16 Ks[64 * 128];       // swizzled [s_local][hd]
  __shared__ u16 Vt[128 * 64];       // swizzled [hd][s_local]
  __shared__ u16 Ps[4][16 * 72];     // per-wave P tile, padded rows
  int tid = threadIdx.x, lane = tid & 63, wid = tid >> 6;
  int quad = lane >> 4, l16 = lane & 15;
  int bx = blockIdx.x;
  int it = 31 - (bx >> 5);           // global longest-first
  int hb = bx & 31;
  int h = hb & 15, b = hb >> 4;
  int kvh = h >> 2;                  // G = 4
  int q0 = it * 64;

  short8 qf[4];
  {
    const u16* qb = qr + ((size_t)(b * S_ + q0 + wid * 16 + l16) * H_ + h) * HD_;
#pragma unroll
    for (int kk = 0; kk < 4; kk++)
      qf[kk] = *(const short8*)(qb + kk * 32 + quad * 8);
  }

  // prefetch pointers: chunk swizzle is j-independent, so 2 bases + strides.
  int gjk = (tid & 15) ^ ((tid >> 4) & 15);
  int gjv = (tid & 7) ^ ((tid >> 3) & 7);
  const u16* kp = kr + ((size_t)(b * S_ + (tid >> 4)) * KVH_ + kvh) * HD_ + gjk * 8;
  const u16* vp = vt + ((size_t)(b * KVH_ + kvh) * HD_ + (tid >> 3)) * S_ + gjv * 8;

  short8 pk[4], pv[4];
#pragma unroll
  for (int j = 0; j < 4; j++) {
    pk[j] = *(const short8*)(kp + (size_t)j * 16 * KVH_ * HD_);
    pv[j] = *(const short8*)(vp + (size_t)j * 32 * S_);
  }

  floatx4 accO[8] = {};
  float m_i[4] = { -__builtin_inff(), -__builtin_inff(), -__builtin_inff(), -__builtin_inff() };
  float l_i[4] = { 0.f, 0.f, 0.f, 0.f };
  u16* PsW = &Ps[wid][0];
  int qrow_hi = q0 + wid * 16 + quad * 4;

  for (int kt = 0; kt <= it; kt++) {
    int k0 = kt * 64;
    // commit prefetched tile to LDS (waits vmcnt here, after prev compute)
#pragma unroll
    for (int j = 0; j < 4; j++) {
      *(short8*)&Ks[(j * 256 + tid) * 8] = pk[j];
      *(short8*)&Vt[(j * 256 + tid) * 8] = pv[j];
    }
    __syncthreads();

    // issue next tile's loads; latency hidden behind compute below
    if (kt < it) {
      kp += (size_t)64 * KVH_ * HD_;
      vp += 64;
#pragma unroll
      for (int j = 0; j < 4; j++) {
        pk[j] = *(const short8*)(kp + (size_t)j * 16 * KVH_ * HD_);
        pv[j] = *(const short8*)(vp + (size_t)j * 32 * S_);
      }
    }

    // S = Q K^T  (16 x 64 per wave)
    floatx4 sacc[4] = {};
#pragma unroll
    for (int kk = 0; kk < 4; kk++)
#pragma unroll
      for (int nt = 0; nt < 4; nt++) {
        int row = nt * 16 + l16;
        short8 kf = *(const short8*)&Ks[row * 128 + (((kk * 4 + quad) ^ (row & 15)) * 8)];
        sacc[nt] = __builtin_amdgcn_mfma_f32_16x16x32_bf16(qf[kk], kf, sacc[nt], 0, 0, 0);
      }

    bool diag = (kt == it);
    float alpha[4];
#pragma unroll
    for (int r = 0; r < 4; r++) {
      int row = qrow_hi + r;
      float mx = -__builtin_inff();
#pragma unroll
      for (int nt = 0; nt < 4; nt++) {
        float s = sacc[nt][r];
        if (diag) s = ((k0 + nt * 16 + l16) <= row) ? s : -__builtin_inff();
        sacc[nt][r] = s;
        mx = fmaxf(mx, s);
      }
#pragma unroll
      for (int d = 1; d < 16; d <<= 1) mx = fmaxf(mx, __shfl_xor(mx, d));
      float mn = fmaxf(m_i[r], mx);
      float al = __expf(m_i[r] - mn);   // exp(-inf)=0 on first tile
      float rsum = 0.f;
#pragma unroll
      for (int nt = 0; nt < 4; nt++) {
        float p = __expf(sacc[nt][r] - mn);
        rsum += p;
        PsW[(quad * 4 + r) * 72 + nt * 16 + l16] = f2bf(p);
      }
#pragma unroll
      for (int d = 1; d < 16; d <<= 1) rsum += __shfl_xor(rsum, d);
      l_i[r] = l_i[r] * al + rsum;
      m_i[r] = mn;
      alpha[r] = al;
    }

#pragma unroll
    for (int ht = 0; ht < 8; ht++)
#pragma unroll
      for (int r = 0; r < 4; r++) accO[ht][r] *= alpha[r];

    // O += P V  (P from per-wave LDS in A-layout, Vt rows give B^T layout)
#pragma unroll
    for (int kk = 0; kk < 2; kk++) {
      short8 pf = *(const short8*)&PsW[l16 * 72 + kk * 32 + quad * 8];
#pragma unroll
      for (int ht = 0; ht < 8; ht++) {
        int row = ht * 16 + l16;
        short8 vf = *(const short8*)&Vt[row * 64 + (((kk * 4 + quad) ^ (row & 7)) * 8)];
        accO[ht] = __builtin_amdgcn_mfma_f32_16x16x32_bf16(pf, vf, accO[ht], 0, 0, 0);
      }
    }
    __syncthreads();   // before next tile overwrites Ks/Vt (lgkm only)
  }

#pragma unroll
  for (int ht = 0; ht < 8; ht++)
#pragma unroll
    for (int r = 0; r < 4; r++) {
      int row = qrow_hi + r;
      att[((size_t)(b * S_ + row) * H_ + h) * HD_ + ht * 16 + l16] = f2bf(accO[ht][r] / l_i[r]);
    }
}

// ---------------------------------------------------------------------------
extern "C" void kernel_launch(void* const* d_in, const int* in_sizes, int n_in,
                              void* d_out, int out_size, void* d_ws, size_t ws_size,
                              hipStream_t stream)
{
  const float* x  = (const float*)d_in[0];   // [B,S,DM] f32
  const float* wq = (const float*)d_in[1];   // [DM, H*HD] f32
  const float* wk = (const float*)d_in[2];   // [DM, KV*HD] f32
  const float* wv = (const float*)d_in[3];   // [DM, KV*HD] f32
  const float* wo = (const float*)d_in[4];   // [H*HD, DM] f32
  const float* qs = (const float*)d_in[5];   // [HD] f32
  const float* ks = (const float*)d_in[6];   // [HD] f32

  char* ws = (char*)d_ws;
  size_t off = 0;
  u16* x_bf   = (u16*)(ws + off); off += (size_t)4096 * 2048 * 2;   // x bf16
  u16* wqkv_t = (u16*)(ws + off); off += (size_t)3072 * 2048 * 2;   // [3072][2048]
  u16* wo_t   = (u16*)(ws + off); off += (size_t)2048 * 2048 * 2;   // [2048][2048]
  u16* C1     = (u16*)(ws + off); off += (size_t)4096 * 3072 * 2;   // qkv bf16
  u16* q_rope = (u16*)(ws + off); off += (size_t)4096 * 16 * 128 * 2;
  u16* k_rope = (u16*)(ws + off); off += (size_t)4096 * 4 * 128 * 2;
  u16* vt     = (u16*)(ws + off); off += (size_t)8 * 128 * 2048 * 2;
  u16* att    = (u16*)(ws + off); off += (size_t)4096 * 2048 * 2;

  // x -> bf16
  k_pack_x<<<8192, 256, 0, stream>>>(x, x_bf, 4096 * 2048 / 4);

  // weight packing: B^T layouts (f32 -> bf16 fused)
  k_transpose_f2b<<<dim3(64, 64), dim3(32, 8), 0, stream>>>(wq, wqkv_t, 2048, 2048);
  k_transpose_f2b<<<dim3(16, 64), dim3(32, 8), 0, stream>>>(wk, wqkv_t + (size_t)2048 * 2048, 2048, 512);
  k_transpose_f2b<<<dim3(16, 64), dim3(32, 8), 0, stream>>>(wv, wqkv_t + (size_t)2560 * 2048, 2048, 512);
  k_transpose_f2b<<<dim3(64, 64), dim3(32, 8), 0, stream>>>(wo, wo_t, 2048, 2048);

  // qkv = x @ [wq|wk|wv]  (bf16 out)
  k_gemm_bt<<<dim3(24, 32), 256, 0, stream>>>(x_bf, wqkv_t, C1, 4096, 3072, 2048, 1);

  k_rmsrope<<<4096, 256, 0, stream>>>(C1, qs, ks, q_rope, k_rope);
  k_pack_vt<<<dim3(64, 4, 8), dim3(32, 8), 0, stream>>>(C1, vt);

  // causal flash: 1024 blocks, globally longest-first
  k_flash<<<dim3(1024), 256, 0, stream>>>(q_rope, k_rope, vt, att);

  // out = att @ wo  (f32 out, matching reference output dtype)
  k_gemm_bt<<<dim3(16, 32), 256, 0, stream>>>(att, wo_t, d_out, 4096, 2048, 2048, 0);

  (void)in_sizes; (void)n_in; (void)out_size; (void)ws_size;
}

// Round 7
// 337.889 us; speedup vs baseline: 1.6291x; 1.0381x over previous
//
#include <hip/hip_runtime.h>
#include <hip/hip_bf16.h>
#include <math.h>

typedef unsigned short u16;
typedef short short8 __attribute__((ext_vector_type(8)));
typedef float floatx4 __attribute__((ext_vector_type(4)));

#define B_   2
#define S_   2048
#define DM_  2048
#define H_   16
#define KVH_ 4
#define HD_  128

__device__ __forceinline__ float bf2f(u16 v) {
  union { unsigned int u; float f; } x; x.u = ((unsigned int)v) << 16; return x.f;
}
__device__ __forceinline__ u16 f2bf(float f) {
  union { float f; unsigned int u; } x; x.f = f;
  unsigned int u = x.u;
  u += 0x7FFFu + ((u >> 16) & 1u);   // RNE; inputs finite
  return (u16)(u >> 16);
}

// async 16B global->LDS (lds dest = wave-uniform base + lane*16)
#define GLDS16(gp, lp) __builtin_amdgcn_global_load_lds( \
    (const __attribute__((address_space(1))) unsigned int*)(const void*)(gp), \
    (__attribute__((address_space(3))) unsigned int*)(void*)(lp), 16, 0, 0)

// ---------------------------------------------------------------------------
// f32 -> bf16 elementwise pack (x): 4 elems/thread
// ---------------------------------------------------------------------------
__global__ __launch_bounds__(256) void k_pack_x(
    const float* __restrict__ src, u16* __restrict__ dst, int n4)
{
  int i = blockIdx.x * 256 + threadIdx.x;
  if (i >= n4) return;
  const float4 v = ((const float4*)src)[i];
  u16 o[4] = { f2bf(v.x), f2bf(v.y), f2bf(v.z), f2bf(v.w) };
  *(unsigned long long*)(dst + (size_t)i * 4) = *(unsigned long long*)o;
}

// ---------------------------------------------------------------------------
// f32 transpose + cast: src R x C row-major (f32) -> dst C x R row-major (bf16)
// ---------------------------------------------------------------------------
__global__ __launch_bounds__(256) void k_transpose_f2b(
    const float* __restrict__ src, u16* __restrict__ dst, int R, int C)
{
  __shared__ float tile[32][33];
  int c0 = blockIdx.x * 32, r0 = blockIdx.y * 32;
  int tx = threadIdx.x, ty = threadIdx.y;   // 32 x 8
#pragma unroll
  for (int j = 0; j < 4; j++)
    tile[ty * 4 + j][tx] = src[(size_t)(r0 + ty * 4 + j) * C + c0 + tx];
  __syncthreads();
#pragma unroll
  for (int j = 0; j < 4; j++)
    dst[(size_t)(c0 + ty * 4 + j) * R + r0 + tx] = f2bf(tile[tx][ty * 4 + j]);
}

// ---------------------------------------------------------------------------
// GEMM: C[M][N] = A[M][K] * Bt[N][K]^T   (bf16 in, f32 accum, f32/bf16 out)
// 128x128 tile, BK=32, 4 waves in 2x2, 4x4 16x16 MFMA tiles per wave (m97)
// LDS chunk-swizzle j ^ ((row>>1)&3): fragment reads 8-way -> 2-way (free)
// ---------------------------------------------------------------------------
__global__ __launch_bounds__(256) void k_gemm_bt(
    const u16* __restrict__ A, const u16* __restrict__ Bt,
    void* __restrict__ Cout, int M, int N, int K, int c_bf16)
{
  __shared__ u16 As[128 * 32];
  __shared__ u16 Bs[128 * 32];
  int tid = threadIdx.x;
  int lane = tid & 63;
  int quad = lane >> 4, l16 = lane & 15;
  int wid = tid >> 6;
  int m0 = blockIdx.y * 128, n0 = blockIdx.x * 128;
  int wm = (wid >> 1) * 64, wn = (wid & 1) * 64;

  floatx4 acc[4][4] = {};

  int arow = tid >> 2;                               // LDS slot row
  int gj = (tid & 3) ^ ((tid >> 3) & 3);             // swizzled global chunk
  const u16* Ap = A + (size_t)(m0 + arow) * K + gj * 8;
  const u16* Bp = Bt + (size_t)(n0 + arow) * K + gj * 8;
  u16* AsW = As + tid * 8;
  u16* BsW = Bs + tid * 8;
  int sw = (quad ^ ((l16 >> 1) & 3)) * 8;            // swizzled read chunk

  for (int kt = 0; kt < K; kt += 32) {
    __syncthreads();                       // protect LDS from prev iter readers
    GLDS16(Ap, AsW);
    GLDS16(Ap + (size_t)64 * K, AsW + 2048);
    GLDS16(Bp, BsW);
    GLDS16(Bp + (size_t)64 * K, BsW + 2048);
    Ap += 32; Bp += 32;
    __syncthreads();                       // drains vmcnt(0) before barrier

    short8 af[4], bfv[4];
#pragma unroll
    for (int mi = 0; mi < 4; mi++)
      af[mi] = *(const short8*)&As[(wm + mi * 16 + l16) * 32 + sw];
#pragma unroll
    for (int ni = 0; ni < 4; ni++)
      bfv[ni] = *(const short8*)&Bs[(wn + ni * 16 + l16) * 32 + sw];
#pragma unroll
    for (int mi = 0; mi < 4; mi++)
#pragma unroll
      for (int ni = 0; ni < 4; ni++)
        acc[mi][ni] = __builtin_amdgcn_mfma_f32_16x16x32_bf16(
            af[mi], bfv[ni], acc[mi][ni], 0, 0, 0);
  }

#pragma unroll
  for (int mi = 0; mi < 4; mi++)
#pragma unroll
    for (int ni = 0; ni < 4; ni++)
#pragma unroll
      for (int r = 0; r < 4; r++) {
        int row = m0 + wm + mi * 16 + quad * 4 + r;
        int col = n0 + wn + ni * 16 + l16;
        float v = acc[mi][ni][r];
        if (c_bf16) ((u16*)Cout)[(size_t)row * N + col] = f2bf(v);
        else        ((float*)Cout)[(size_t)row * N + col] = v;
      }
}

// ---------------------------------------------------------------------------
// RMSNorm + RoPE on the qkv GEMM output (bf16), emit bf16 q_rope / k_rope.
// ---------------------------------------------------------------------------
__global__ __launch_bounds__(256) void k_rmsrope(
    const u16* __restrict__ C1, const float* __restrict__ qs,
    const float* __restrict__ ks, u16* __restrict__ qr, u16* __restrict__ kr)
{
  int m = blockIdx.x;
  int lane = threadIdx.x & 63, wid = threadIdx.x >> 6;
  int pos = m & (S_ - 1);
  float ts = powf(10000.0f, (float)lane * (1.0f / 64.0f));
  float ang = (float)pos / ts;
  float sn = sinf(ang), cs = cosf(ang);
  for (int r = wid; r < H_ + KVH_; r += 4) {
    bool isq = r < H_;
    const u16* src = C1 + (size_t)m * 3072 + (isq ? r * HD_ : DM_ + (r - H_) * HD_);
    float x1 = bf2f(src[lane]), x2 = bf2f(src[lane + 64]);
    float ss = x1 * x1 + x2 * x2;
#pragma unroll
    for (int d = 1; d < 64; d <<= 1) ss += __shfl_xor(ss, d);
    float rs = rsqrtf(ss * (1.0f / 128.0f) + 1e-6f);
    const float* sc = isq ? qs : ks;
    float y1 = x1 * rs * sc[lane];
    float y2 = x2 * rs * sc[lane + 64];
    float o1 = y1 * cs - y2 * sn;
    float o2 = y2 * cs + y1 * sn;
    if (isq) { o1 *= 0.088388347648318447f; o2 *= 0.088388347648318447f; }
    u16* dst = isq ? (qr + ((size_t)m * H_ + r) * HD_)
                   : (kr + ((size_t)m * KVH_ + (r - H_)) * HD_);
    dst[lane]      = f2bf(o1);
    dst[lane + 64] = f2bf(o2);
  }
}

// ---------------------------------------------------------------------------
// Pack V (bf16 cols 2560..3071 of C1) into bf16 vt[b][kv][HD][S] (transposed)
// ---------------------------------------------------------------------------
__global__ __launch_bounds__(256) void k_pack_vt(
    const u16* __restrict__ C1, u16* __restrict__ vt)
{
  __shared__ u16 tile[32][33];
  int s0 = blockIdx.x * 32, h0 = blockIdx.y * 32;
  int bk = blockIdx.z;                 // b*KV + kv
  int b = bk >> 2, kv = bk & 3;
  int tx = threadIdx.x, ty = threadIdx.y;
#pragma unroll
  for (int j = 0; j < 4; j++)
    tile[ty * 4 + j][tx] =
        C1[(size_t)(b * S_ + s0 + ty * 4 + j) * 3072 + 2560 + kv * HD_ + h0 + tx];
  __syncthreads();
#pragma unroll
  for (int j = 0; j < 4; j++)
    vt[((size_t)bk * HD_ + h0 + ty * 4 + j) * S_ + s0 + tx] = tile[tx][ty * 4 + j];
}

// ---------------------------------------------------------------------------
// Flash attention, register-prefetch pipeline + global longest-first order.
// FIXED-MAX softmax: after RMSNorm, Cauchy-Schwarz bounds |score| <= 11.32
// (||q*HD^-0.5||=1, ||k||=sqrt(128)), so exp(s - 12.5) never overflows and
// online-max bookkeeping (max-reduce, sum-reduce, alpha rescale, m_i chain)
// is deleted; l is a per-lane partial reduced ONCE at the end.
// ---------------------------------------------------------------------------
__global__ __launch_bounds__(256, 3) void k_flash(
    const u16* __restrict__ qr, const u16* __restrict__ kr,
    const u16* __restrict__ vt, u16* __restrict__ att)
{
  __shared__ u16 Ks[64 * 128];       // swizzled [s_local][hd]
  __shared__ u16 Vt[128 * 64];       // swizzled [hd][s_local]
  __shared__ u16 Ps[4][16 * 72];     // per-wave P tile, padded rows
  int tid = threadIdx.x, lane = tid & 63, wid = tid >> 6;
  int quad = lane >> 4, l16 = lane & 15;
  int bx = blockIdx.x;
  int it = 31 - (bx >> 5);           // global longest-first
  int hb = bx & 31;
  int h = hb & 15, b = hb >> 4;
  int kvh = h >> 2;                  // G = 4
  int q0 = it * 64;

  short8 qf[4];
  {
    const u16* qb = qr + ((size_t)(b * S_ + q0 + wid * 16 + l16) * H_ + h) * HD_;
#pragma unroll
    for (int kk = 0; kk < 4; kk++)
      qf[kk] = *(const short8*)(qb + kk * 32 + quad * 8);
  }

  // prefetch pointers: chunk swizzle is j-independent, so 2 bases + strides.
  int gjk = (tid & 15) ^ ((tid >> 4) & 15);
  int gjv = (tid & 7) ^ ((tid >> 3) & 7);
  const u16* kp = kr + ((size_t)(b * S_ + (tid >> 4)) * KVH_ + kvh) * HD_ + gjk * 8;
  const u16* vp = vt + ((size_t)(b * KVH_ + kvh) * HD_ + (tid >> 3)) * S_ + gjv * 8;

  short8 pk[4], pv[4];
#pragma unroll
  for (int j = 0; j < 4; j++) {
    pk[j] = *(const short8*)(kp + (size_t)j * 16 * KVH_ * HD_);
    pv[j] = *(const short8*)(vp + (size_t)j * 32 * S_);
  }

  floatx4 accO[8] = {};
  float lp[4] = { 0.f, 0.f, 0.f, 0.f };   // per-lane partial denominators
  u16* PsW = &Ps[wid][0];
  int qrow_hi = q0 + wid * 16 + quad * 4;

  // exp(s - 12.5) = exp2(s*log2e - 12.5*log2e)
  const float LOG2E = 1.4426950408889634f;
  const float MBIAS = -12.5f * 1.4426950408889634f;

  for (int kt = 0; kt <= it; kt++) {
    int k0 = kt * 64;
    // commit prefetched tile to LDS (waits vmcnt here, after prev compute)
#pragma unroll
    for (int j = 0; j < 4; j++) {
      *(short8*)&Ks[(j * 256 + tid) * 8] = pk[j];
      *(short8*)&Vt[(j * 256 + tid) * 8] = pv[j];
    }
    __syncthreads();

    // issue next tile's loads; latency hidden behind compute below
    if (kt < it) {
      kp += (size_t)64 * KVH_ * HD_;
      vp += 64;
#pragma unroll
      for (int j = 0; j < 4; j++) {
        pk[j] = *(const short8*)(kp + (size_t)j * 16 * KVH_ * HD_);
        pv[j] = *(const short8*)(vp + (size_t)j * 32 * S_);
      }
    }

    // S = Q K^T  (16 x 64 per wave)
    floatx4 sacc[4] = {};
#pragma unroll
    for (int kk = 0; kk < 4; kk++)
#pragma unroll
      for (int nt = 0; nt < 4; nt++) {
        int row = nt * 16 + l16;
        short8 kf = *(const short8*)&Ks[row * 128 + (((kk * 4 + quad) ^ (row & 15)) * 8)];
        sacc[nt] = __builtin_amdgcn_mfma_f32_16x16x32_bf16(qf[kk], kf, sacc[nt], 0, 0, 0);
      }

    bool diag = (kt == it);
#pragma unroll
    for (int r = 0; r < 4; r++) {
      int row = qrow_hi + r;
      float rsum = 0.f;
#pragma unroll
      for (int nt = 0; nt < 4; nt++) {
        float p = __builtin_amdgcn_exp2f(fmaf(sacc[nt][r], LOG2E, MBIAS));
        if (diag && (k0 + nt * 16 + l16) > row) p = 0.f;
        rsum += p;
        PsW[(quad * 4 + r) * 72 + nt * 16 + l16] = f2bf(p);
      }
      lp[r] += rsum;
    }

    // O += P V  (P from per-wave LDS in A-layout, Vt rows give B^T layout)
#pragma unroll
    for (int kk = 0; kk < 2; kk++) {
      short8 pf = *(const short8*)&PsW[l16 * 72 + kk * 32 + quad * 8];
#pragma unroll
      for (int ht = 0; ht < 8; ht++) {
        int row = ht * 16 + l16;
        short8 vf = *(const short8*)&Vt[row * 64 + (((kk * 4 + quad) ^ (row & 7)) * 8)];
        accO[ht] = __builtin_amdgcn_mfma_f32_16x16x32_bf16(pf, vf, accO[ht], 0, 0, 0);
      }
    }
    __syncthreads();   // before next tile overwrites Ks/Vt (lgkm only)
  }

  // single end-of-kernel 16-lane reduction of the denominators
#pragma unroll
  for (int r = 0; r < 4; r++) {
#pragma unroll
    for (int d = 1; d < 16; d <<= 1) lp[r] += __shfl_xor(lp[r], d);
    lp[r] = 1.0f / lp[r];
  }

#pragma unroll
  for (int ht = 0; ht < 8; ht++)
#pragma unroll
    for (int r = 0; r < 4; r++) {
      int row = qrow_hi + r;
      att[((size_t)(b * S_ + row) * H_ + h) * HD_ + ht * 16 + l16] = f2bf(accO[ht][r] * lp[r]);
    }
}

// ---------------------------------------------------------------------------
extern "C" void kernel_launch(void* const* d_in, const int* in_sizes, int n_in,
                              void* d_out, int out_size, void* d_ws, size_t ws_size,
                              hipStream_t stream)
{
  const float* x  = (const float*)d_in[0];   // [B,S,DM] f32
  const float* wq = (const float*)d_in[1];   // [DM, H*HD] f32
  const float* wk = (const float*)d_in[2];   // [DM, KV*HD] f32
  const float* wv = (const float*)d_in[3];   // [DM, KV*HD] f32
  const float* wo = (const float*)d_in[4];   // [H*HD, DM] f32
  const float* qs = (const float*)d_in[5];   // [HD] f32
  const float* ks = (const float*)d_in[6];   // [HD] f32

  char* ws = (char*)d_ws;
  size_t off = 0;
  u16* x_bf   = (u16*)(ws + off); off += (size_t)4096 * 2048 * 2;   // x bf16
  u16* wqkv_t = (u16*)(ws + off); off += (size_t)3072 * 2048 * 2;   // [3072][2048]
  u16* wo_t   = (u16*)(ws + off); off += (size_t)2048 * 2048 * 2;   // [2048][2048]
  u16* C1     = (u16*)(ws + off); off += (size_t)4096 * 3072 * 2;   // qkv bf16
  u16* q_rope = (u16*)(ws + off); off += (size_t)4096 * 16 * 128 * 2;
  u16* k_rope = (u16*)(ws + off); off += (size_t)4096 * 4 * 128 * 2;
  u16* vt     = (u16*)(ws + off); off += (size_t)8 * 128 * 2048 * 2;
  u16* att    = (u16*)(ws + off); off += (size_t)4096 * 2048 * 2;

  // x -> bf16
  k_pack_x<<<8192, 256, 0, stream>>>(x, x_bf, 4096 * 2048 / 4);

  // weight packing: B^T layouts (f32 -> bf16 fused)
  k_transpose_f2b<<<dim3(64, 64), dim3(32, 8), 0, stream>>>(wq, wqkv_t, 2048, 2048);
  k_transpose_f2b<<<dim3(16, 64), dim3(32, 8), 0, stream>>>(wk, wqkv_t + (size_t)2048 * 2048, 2048, 512);
  k_transpose_f2b<<<dim3(16, 64), dim3(32, 8), 0, stream>>>(wv, wqkv_t + (size_t)2560 * 2048, 2048, 512);
  k_transpose_f2b<<<dim3(64, 64), dim3(32, 8), 0, stream>>>(wo, wo_t, 2048, 2048);

  // qkv = x @ [wq|wk|wv]  (bf16 out)
  k_gemm_bt<<<dim3(24, 32), 256, 0, stream>>>(x_bf, wqkv_t, C1, 4096, 3072, 2048, 1);

  k_rmsrope<<<4096, 256, 0, stream>>>(C1, qs, ks, q_rope, k_rope);
  k_pack_vt<<<dim3(64, 4, 8), dim3(32, 8), 0, stream>>>(C1, vt);

  // causal flash: 1024 blocks, globally longest-first
  k_flash<<<dim3(1024), 256, 0, stream>>>(q_rope, k_rope, vt, att);

  // out = att @ wo  (f32 out, matching reference output dtype)
  k_gemm_bt<<<dim3(16, 32), 256, 0, stream>>>(att, wo_t, d_out, 4096, 2048, 2048, 0);

  (void)in_sizes; (void)n_in; (void)out_size; (void)ws_size;
}

// Round 8
// 297.292 us; speedup vs baseline: 1.8516x; 1.1366x over previous
//
#include <hip/hip_runtime.h>
#include <hip/hip_bf16.h>
#include <math.h>

typedef unsigned short u16;
typedef short short8 __attribute__((ext_vector_type(8)));
typedef float floatx4 __attribute__((ext_vector_type(4)));

#define B_   2
#define S_   2048
#define DM_  2048
#define H_   16
#define KVH_ 4
#define HD_  128

__device__ __forceinline__ float bf2f(u16 v) {
  union { unsigned int u; float f; } x; x.u = ((unsigned int)v) << 16; return x.f;
}
__device__ __forceinline__ u16 f2bf(float f) {
  union { float f; unsigned int u; } x; x.f = f;
  unsigned int u = x.u;
  u += 0x7FFFu + ((u >> 16) & 1u);   // RNE; inputs finite
  return (u16)(u >> 16);
}

// async 16B global->LDS (lds dest = wave-uniform base + lane*16)
#define GLDS16(gp, lp) __builtin_amdgcn_global_load_lds( \
    (const __attribute__((address_space(1))) unsigned int*)(const void*)(gp), \
    (__attribute__((address_space(3))) unsigned int*)(void*)(lp), 16, 0, 0)

// ---------------------------------------------------------------------------
// k_prep: pack_x (blocks 0..8191) + 4 weight transposes (blocks 8192..18431)
// merged into one launch (block-uniform branching).
// ---------------------------------------------------------------------------
__global__ __launch_bounds__(256) void k_prep(
    const float* __restrict__ x, const float* __restrict__ wq,
    const float* __restrict__ wk, const float* __restrict__ wv,
    const float* __restrict__ wo,
    u16* __restrict__ x_bf, u16* __restrict__ wqkv_t, u16* __restrict__ wo_t)
{
  int bx = blockIdx.x;
  if (bx < 8192) {                       // x -> bf16, 4 elems/thread
    int i = bx * 256 + threadIdx.x;
    const float4 v = ((const float4*)x)[i];
    u16 o[4] = { f2bf(v.x), f2bf(v.y), f2bf(v.z), f2bf(v.w) };
    *(unsigned long long*)(x_bf + (size_t)i * 4) = *(unsigned long long*)o;
    return;
  }
  bx -= 8192;
  const float* src; u16* dst; int C, cb;
  if (bx < 4096)      { src = wq; dst = wqkv_t; C = 2048; cb = 64; }
  else if (bx < 5120) { bx -= 4096; src = wk; dst = wqkv_t + (size_t)2048 * 2048; C = 512; cb = 16; }
  else if (bx < 6144) { bx -= 5120; src = wv; dst = wqkv_t + (size_t)2560 * 2048; C = 512; cb = 16; }
  else                { bx -= 6144; src = wo; dst = wo_t; C = 2048; cb = 64; }
  const int R = 2048;
  int c0 = (bx % cb) * 32, r0 = (bx / cb) * 32;
  __shared__ float tile[32][33];
  int tx = threadIdx.x & 31, ty = threadIdx.x >> 5;
#pragma unroll
  for (int j = 0; j < 4; j++)
    tile[ty * 4 + j][tx] = src[(size_t)(r0 + ty * 4 + j) * C + c0 + tx];
  __syncthreads();
#pragma unroll
  for (int j = 0; j < 4; j++)
    dst[(size_t)(c0 + ty * 4 + j) * R + r0 + tx] = f2bf(tile[tx][ty * 4 + j]);
}

// ---------------------------------------------------------------------------
// GEMM: C[M][N] = A[M][K] * Bt[N][K]^T   (bf16 in, f32 accum, f32/bf16 out)
// 128x128 tile, BK=64 (32 KB LDS): 32 MFMA per barrier pair (AITER ratio).
// LDS row = 8 chunks of 16B; swizzle chunk ^ (row&7) kills bank conflicts.
// ---------------------------------------------------------------------------
__global__ __launch_bounds__(256, 3) void k_gemm_bt(
    const u16* __restrict__ A, const u16* __restrict__ Bt,
    void* __restrict__ Cout, int M, int N, int K, int c_bf16)
{
  __shared__ u16 As[128 * 64];
  __shared__ u16 Bs[128 * 64];
  int tid = threadIdx.x;
  int lane = tid & 63;
  int quad = lane >> 4, l16 = lane & 15;
  int wid = tid >> 6;
  int m0 = blockIdx.y * 128, n0 = blockIdx.x * 128;
  int wm = (wid >> 1) * 64, wn = (wid & 1) * 64;

  floatx4 acc[4][4] = {};

  // staging: c = j*256 + tid -> row = c>>3 (j adds 32 rows; row&7 invariant),
  // LDS chunkpos = c&7 holds global chunk (c&7) ^ (row&7)
  int srow = tid >> 3;
  int gjc0 = (tid & 7) ^ (srow & 7);
  const u16* Ap = A + (size_t)(m0 + srow) * K + gjc0 * 8;
  const u16* Bp = Bt + (size_t)(n0 + srow) * K + gjc0 * 8;
  u16* AsW = As + tid * 8;
  u16* BsW = Bs + tid * 8;

  for (int kt = 0; kt < K; kt += 64) {
    __syncthreads();                     // protect LDS from prev iter readers
#pragma unroll
    for (int j = 0; j < 4; j++) {
      GLDS16(Ap + (size_t)(j * 32) * K, AsW + j * 2048);
      GLDS16(Bp + (size_t)(j * 32) * K, BsW + j * 2048);
    }
    Ap += 64; Bp += 64;
    __syncthreads();                     // drains vmcnt(0)

#pragma unroll
    for (int ks = 0; ks < 2; ks++) {
      short8 af[4], bfv[4];
#pragma unroll
      for (int mi = 0; mi < 4; mi++) {
        int row = wm + mi * 16 + l16;
        af[mi] = *(const short8*)&As[row * 64 + (((ks * 4 + quad) ^ (row & 7)) * 8)];
      }
#pragma unroll
      for (int ni = 0; ni < 4; ni++) {
        int row = wn + ni * 16 + l16;
        bfv[ni] = *(const short8*)&Bs[row * 64 + (((ks * 4 + quad) ^ (row & 7)) * 8)];
      }
#pragma unroll
      for (int mi = 0; mi < 4; mi++)
#pragma unroll
        for (int ni = 0; ni < 4; ni++)
          acc[mi][ni] = __builtin_amdgcn_mfma_f32_16x16x32_bf16(
              af[mi], bfv[ni], acc[mi][ni], 0, 0, 0);
    }
  }

#pragma unroll
  for (int mi = 0; mi < 4; mi++)
#pragma unroll
    for (int ni = 0; ni < 4; ni++)
#pragma unroll
      for (int r = 0; r < 4; r++) {
        int row = m0 + wm + mi * 16 + quad * 4 + r;
        int col = n0 + wn + ni * 16 + l16;
        float v = acc[mi][ni][r];
        if (c_bf16) ((u16*)Cout)[(size_t)row * N + col] = f2bf(v);
        else        ((float*)Cout)[(size_t)row * N + col] = v;
      }
}

// ---------------------------------------------------------------------------
// k_post: RMSNorm+RoPE (blocks 0..4095) + pack_vt (blocks 4096..6143) merged.
// ---------------------------------------------------------------------------
__global__ __launch_bounds__(256) void k_post(
    const u16* __restrict__ C1, const float* __restrict__ qs,
    const float* __restrict__ ks, u16* __restrict__ qr, u16* __restrict__ kr,
    u16* __restrict__ vt)
{
  int bx = blockIdx.x;
  if (bx < 4096) {                       // rmsnorm + rope
    int m = bx;
    int lane = threadIdx.x & 63, wid = threadIdx.x >> 6;
    int pos = m & (S_ - 1);
    float ts = powf(10000.0f, (float)lane * (1.0f / 64.0f));
    float ang = (float)pos / ts;
    float sn = sinf(ang), cs = cosf(ang);
    for (int r = wid; r < H_ + KVH_; r += 4) {
      bool isq = r < H_;
      const u16* src = C1 + (size_t)m * 3072 + (isq ? r * HD_ : DM_ + (r - H_) * HD_);
      float x1 = bf2f(src[lane]), x2 = bf2f(src[lane + 64]);
      float ss = x1 * x1 + x2 * x2;
#pragma unroll
      for (int d = 1; d < 64; d <<= 1) ss += __shfl_xor(ss, d);
      float rs = rsqrtf(ss * (1.0f / 128.0f) + 1e-6f);
      const float* sc = isq ? qs : ks;
      float y1 = x1 * rs * sc[lane];
      float y2 = x2 * rs * sc[lane + 64];
      float o1 = y1 * cs - y2 * sn;
      float o2 = y2 * cs + y1 * sn;
      if (isq) { o1 *= 0.088388347648318447f; o2 *= 0.088388347648318447f; }
      u16* dst = isq ? (qr + ((size_t)m * H_ + r) * HD_)
                     : (kr + ((size_t)m * KVH_ + (r - H_)) * HD_);
      dst[lane]      = f2bf(o1);
      dst[lane + 64] = f2bf(o2);
    }
    return;
  }
  bx -= 4096;                            // pack_vt: decode 64 x 4 x 8
  int sx = bx & 63, rest = bx >> 6;
  int hy = rest & 3, bk = rest >> 2;
  int s0 = sx * 32, h0 = hy * 32;
  int b = bk >> 2, kv = bk & 3;
  __shared__ u16 tile[32][33];
  int tx = threadIdx.x & 31, ty = threadIdx.x >> 5;
#pragma unroll
  for (int j = 0; j < 4; j++)
    tile[ty * 4 + j][tx] =
        C1[(size_t)(b * S_ + s0 + ty * 4 + j) * 3072 + 2560 + kv * HD_ + h0 + tx];
  __syncthreads();
#pragma unroll
  for (int j = 0; j < 4; j++)
    vt[((size_t)bk * HD_ + h0 + ty * 4 + j) * S_ + s0 + tx] = tile[tx][ty * 4 + j];
}

// ---------------------------------------------------------------------------
// Flash attention, register-prefetch pipeline + global longest-first order.
// FIXED-MAX softmax (Cauchy-Schwarz bound |score| <= 11.32 post-RMSNorm).
// ---------------------------------------------------------------------------
__global__ __launch_bounds__(256, 3) void k_flash(
    const u16* __restrict__ qr, const u16* __restrict__ kr,
    const u16* __restrict__ vt, u16* __restrict__ att)
{
  __shared__ u16 Ks[64 * 128];       // swizzled [s_local][hd]
  __shared__ u16 Vt[128 * 64];       // swizzled [hd][s_local]
  __shared__ u16 Ps[4][16 * 72];     // per-wave P tile, padded rows
  int tid = threadIdx.x, lane = tid & 63, wid = tid >> 6;
  int quad = lane >> 4, l16 = lane & 15;
  int bx = blockIdx.x;
  int it = 31 - (bx >> 5);           // global longest-first
  int hb = bx & 31;
  int h = hb & 15, b = hb >> 4;
  int kvh = h >> 2;                  // G = 4
  int q0 = it * 64;

  short8 qf[4];
  {
    const u16* qb = qr + ((size_t)(b * S_ + q0 + wid * 16 + l16) * H_ + h) * HD_;
#pragma unroll
    for (int kk = 0; kk < 4; kk++)
      qf[kk] = *(const short8*)(qb + kk * 32 + quad * 8);
  }

  int gjk = (tid & 15) ^ ((tid >> 4) & 15);
  int gjv = (tid & 7) ^ ((tid >> 3) & 7);
  const u16* kp = kr + ((size_t)(b * S_ + (tid >> 4)) * KVH_ + kvh) * HD_ + gjk * 8;
  const u16* vp = vt + ((size_t)(b * KVH_ + kvh) * HD_ + (tid >> 3)) * S_ + gjv * 8;

  short8 pk[4], pv[4];
#pragma unroll
  for (int j = 0; j < 4; j++) {
    pk[j] = *(const short8*)(kp + (size_t)j * 16 * KVH_ * HD_);
    pv[j] = *(const short8*)(vp + (size_t)j * 32 * S_);
  }

  floatx4 accO[8] = {};
  float lp[4] = { 0.f, 0.f, 0.f, 0.f };   // per-lane partial denominators
  u16* PsW = &Ps[wid][0];
  int qrow_hi = q0 + wid * 16 + quad * 4;

  const float LOG2E = 1.4426950408889634f;
  const float MBIAS = -12.5f * 1.4426950408889634f;

  for (int kt = 0; kt <= it; kt++) {
    int k0 = kt * 64;
#pragma unroll
    for (int j = 0; j < 4; j++) {
      *(short8*)&Ks[(j * 256 + tid) * 8] = pk[j];
      *(short8*)&Vt[(j * 256 + tid) * 8] = pv[j];
    }
    __syncthreads();

    if (kt < it) {
      kp += (size_t)64 * KVH_ * HD_;
      vp += 64;
#pragma unroll
      for (int j = 0; j < 4; j++) {
        pk[j] = *(const short8*)(kp + (size_t)j * 16 * KVH_ * HD_);
        pv[j] = *(const short8*)(vp + (size_t)j * 32 * S_);
      }
    }

    floatx4 sacc[4] = {};
#pragma unroll
    for (int kk = 0; kk < 4; kk++)
#pragma unroll
      for (int nt = 0; nt < 4; nt++) {
        int row = nt * 16 + l16;
        short8 kf = *(const short8*)&Ks[row * 128 + (((kk * 4 + quad) ^ (row & 15)) * 8)];
        sacc[nt] = __builtin_amdgcn_mfma_f32_16x16x32_bf16(qf[kk], kf, sacc[nt], 0, 0, 0);
      }

    bool diag = (kt == it);
#pragma unroll
    for (int r = 0; r < 4; r++) {
      int row = qrow_hi + r;
      float rsum = 0.f;
#pragma unroll
      for (int nt = 0; nt < 4; nt++) {
        float p = __builtin_amdgcn_exp2f(fmaf(sacc[nt][r], LOG2E, MBIAS));
        if (diag && (k0 + nt * 16 + l16) > row) p = 0.f;
        rsum += p;
        PsW[(quad * 4 + r) * 72 + nt * 16 + l16] = f2bf(p);
      }
      lp[r] += rsum;
    }

#pragma unroll
    for (int kk = 0; kk < 2; kk++) {
      short8 pf = *(const short8*)&PsW[l16 * 72 + kk * 32 + quad * 8];
#pragma unroll
      for (int ht = 0; ht < 8; ht++) {
        int row = ht * 16 + l16;
        short8 vf = *(const short8*)&Vt[row * 64 + (((kk * 4 + quad) ^ (row & 7)) * 8)];
        accO[ht] = __builtin_amdgcn_mfma_f32_16x16x32_bf16(pf, vf, accO[ht], 0, 0, 0);
      }
    }
    __syncthreads();
  }

#pragma unroll
  for (int r = 0; r < 4; r++) {
#pragma unroll
    for (int d = 1; d < 16; d <<= 1) lp[r] += __shfl_xor(lp[r], d);
    lp[r] = 1.0f / lp[r];
  }

#pragma unroll
  for (int ht = 0; ht < 8; ht++)
#pragma unroll
    for (int r = 0; r < 4; r++) {
      int row = qrow_hi + r;
      att[((size_t)(b * S_ + row) * H_ + h) * HD_ + ht * 16 + l16] = f2bf(accO[ht][r] * lp[r]);
    }
}

// ---------------------------------------------------------------------------
extern "C" void kernel_launch(void* const* d_in, const int* in_sizes, int n_in,
                              void* d_out, int out_size, void* d_ws, size_t ws_size,
                              hipStream_t stream)
{
  const float* x  = (const float*)d_in[0];   // [B,S,DM] f32
  const float* wq = (const float*)d_in[1];   // [DM, H*HD] f32
  const float* wk = (const float*)d_in[2];   // [DM, KV*HD] f32
  const float* wv = (const float*)d_in[3];   // [DM, KV*HD] f32
  const float* wo = (const float*)d_in[4];   // [H*HD, DM] f32
  const float* qs = (const float*)d_in[5];   // [HD] f32
  const float* ks = (const float*)d_in[6];   // [HD] f32

  char* ws = (char*)d_ws;
  size_t off = 0;
  u16* x_bf   = (u16*)(ws + off); off += (size_t)4096 * 2048 * 2;   // x bf16
  u16* wqkv_t = (u16*)(ws + off); off += (size_t)3072 * 2048 * 2;   // [3072][2048]
  u16* wo_t   = (u16*)(ws + off); off += (size_t)2048 * 2048 * 2;   // [2048][2048]
  u16* C1     = (u16*)(ws + off); off += (size_t)4096 * 3072 * 2;   // qkv bf16
  u16* q_rope = (u16*)(ws + off); off += (size_t)4096 * 16 * 128 * 2;
  u16* k_rope = (u16*)(ws + off); off += (size_t)4096 * 4 * 128 * 2;
  u16* vt     = (u16*)(ws + off); off += (size_t)8 * 128 * 2048 * 2;
  u16* att    = (u16*)(ws + off); off += (size_t)4096 * 2048 * 2;

  // pack x + all weight transposes, one launch
  k_prep<<<dim3(18432), 256, 0, stream>>>(x, wq, wk, wv, wo, x_bf, wqkv_t, wo_t);

  // qkv = x @ [wq|wk|wv]  (bf16 out)
  k_gemm_bt<<<dim3(24, 32), 256, 0, stream>>>(x_bf, wqkv_t, C1, 4096, 3072, 2048, 1);

  // rmsnorm+rope + v-transpose, one launch
  k_post<<<dim3(6144), 256, 0, stream>>>(C1, qs, ks, q_rope, k_rope, vt);

  // causal flash: 1024 blocks, globally longest-first
  k_flash<<<dim3(1024), 256, 0, stream>>>(q_rope, k_rope, vt, att);

  // out = att @ wo  (f32 out, matching reference output dtype)
  k_gemm_bt<<<dim3(16, 32), 256, 0, stream>>>(att, wo_t, d_out, 4096, 2048, 2048, 0);

  (void)in_sizes; (void)n_in; (void)out_size; (void)ws_size;
}